// Round 12
// baseline (4880.639 us; speedup 1.0000x reference)
//
#include <hip/hip_runtime.h>
#include <math.h>

// B=16, S=128, H=512, V=50000, N=5, R=2, Wd=512, XI=2573
#define EPSC 1e-6f
#define NBLK 128
#define GBLK 64     // blocks per group; 2 independent groups of 8 batches

// ws layout (float offsets)
#define OFF_H     0u         // hbuf[2][16][512]
#define OFF_R     16384u     // r[16][1024]
#define OFF_FLAGS 32768u     // bar1 arrival flags: 128 x 32 u32
#define OFF_GO    36864u     // bar1 go lines:      128 x 32 u32
#define OFF_XF    40960u     // xi-producer flags:  128 x 32 u32
#define OFF_RF    45056u     // r-producer flags:   16 x 32 u32 (+pad)
#define STATE_END 46080u
#define OFF_XI    46080u     // xi[16][3072] (padded rows)
#define OFF_GX    95232u     // gates_x[128][16][2048]
#define OFF_HR    4289536u   // hr[128][16][1536]
// end 7435264 floats = 29.74 MB

typedef float f32x4 __attribute__((ext_vector_type(4)));

__device__ __forceinline__ float sigmf(float x) { return 1.0f / (1.0f + expf(-x)); }
__device__ __forceinline__ float oneplusf(float x) {
    return 1.0f + fmaxf(x, 0.0f) + log1pf(expf(-fabsf(x)));
}

// coherent scalar store (agent scope, bypasses L1/L2) — proven r3-r11
__device__ __forceinline__ void gst(float* p, float v) {
    __hip_atomic_store((unsigned*)p, __float_as_uint(v),
                       __ATOMIC_RELAXED, __HIP_MEMORY_SCOPE_AGENT);
}

// 8 coherent dwordx4 loads, one base, offsets 0..3584 step 512 B (r-part).
__device__ __forceinline__ void ld8r(
    f32x4& r0, f32x4& r1, f32x4& r2, f32x4& r3,
    f32x4& r4, f32x4& r5, f32x4& r6, f32x4& r7, const float* pr)
{
    asm volatile(
        "global_load_dwordx4 %0, %8, off sc0 sc1\n\t"
        "global_load_dwordx4 %1, %8, off offset:512 sc0 sc1\n\t"
        "global_load_dwordx4 %2, %8, off offset:1024 sc0 sc1\n\t"
        "global_load_dwordx4 %3, %8, off offset:1536 sc0 sc1\n\t"
        "global_load_dwordx4 %4, %8, off offset:2048 sc0 sc1\n\t"
        "global_load_dwordx4 %5, %8, off offset:2560 sc0 sc1\n\t"
        "global_load_dwordx4 %6, %8, off offset:3072 sc0 sc1\n\t"
        "global_load_dwordx4 %7, %8, off offset:3584 sc0 sc1\n\t"
        "s_waitcnt vmcnt(0)"
        : "=&v"(r0), "=&v"(r1), "=&v"(r2), "=&v"(r3),
          "=&v"(r4), "=&v"(r5), "=&v"(r6), "=&v"(r7)
        : "v"(pr)
        : "memory");
}

// 4 coherent dwordx4 loads from one base, offsets 0/512/1024/1536 B.
__device__ __forceinline__ void ld4o(
    f32x4& d0, f32x4& d1, f32x4& d2, f32x4& d3, const float* p)
{
    asm volatile(
        "global_load_dwordx4 %0, %4, off sc0 sc1\n\t"
        "global_load_dwordx4 %1, %4, off offset:512 sc0 sc1\n\t"
        "global_load_dwordx4 %2, %4, off offset:1024 sc0 sc1\n\t"
        "global_load_dwordx4 %3, %4, off offset:1536 sc0 sc1\n\t"
        "s_waitcnt vmcnt(0)"
        : "=&v"(d0), "=&v"(d1), "=&v"(d2), "=&v"(d3)
        : "v"(p)
        : "memory");
}

__device__ __forceinline__ void cld3(
    f32x4& d0, f32x4& d1, f32x4& d2,
    const float* p0, const float* p1, const float* p2)
{
    asm volatile(
        "global_load_dwordx4 %0, %3, off sc0 sc1\n\t"
        "global_load_dwordx4 %1, %4, off sc0 sc1\n\t"
        "global_load_dwordx4 %2, %5, off sc0 sc1\n\t"
        "s_waitcnt vmcnt(0)"
        : "=&v"(d0), "=&v"(d1), "=&v"(d2)
        : "v"(p0), "v"(p1), "v"(p2)
        : "memory");
}

// Fence-free 2-hop mailbox barrier, PER GROUP (1 poller per line).
__device__ __forceinline__ void gsync(unsigned* flags, unsigned* go, unsigned gen,
                                      int bi, int bl, int g, int tid)
{
    __builtin_amdgcn_s_waitcnt(0);   // drain this wave's payload stores
    __syncthreads();
    if (tid == 0)
        __hip_atomic_store(&flags[bi * 32], gen, __ATOMIC_RELAXED, __HIP_MEMORY_SCOPE_AGENT);
    if (bl == 0) {
        if (tid < GBLK) {
            unsigned v;
            do {
                v = __hip_atomic_load(&flags[(g * GBLK + tid) * 32], __ATOMIC_RELAXED,
                                      __HIP_MEMORY_SCOPE_AGENT);
                if (v < gen) __builtin_amdgcn_s_sleep(1);
            } while (v < gen);
        }
        __syncthreads();
        if (tid < GBLK)
            __hip_atomic_store(&go[(g * GBLK + tid) * 32], gen, __ATOMIC_RELAXED,
                               __HIP_MEMORY_SCOPE_AGENT);
    }
    if (tid == 0) {
        unsigned v;
        do {
            v = __hip_atomic_load(&go[bi * 32], __ATOMIC_RELAXED, __HIP_MEMORY_SCOPE_AGENT);
            if (v < gen) __builtin_amdgcn_s_sleep(1);
        } while (v < gen);
    }
    __syncthreads();
}

template <int K>
__device__ __forceinline__ void blk_reduce(float* v, float (*s_red)[20],
                                           float* outp, int tid)
{
#pragma unroll
    for (int i = 0; i < K; i++) {
        float x = v[i];
        for (int o = 32; o > 0; o >>= 1) x += __shfl_down(x, o, 64);
        if ((tid & 63) == 0) s_red[tid >> 6][i] = x;
    }
    __syncthreads();
    if (tid < K) outp[tid] = s_red[0][tid] + s_red[1][tid] + s_red[2][tid] + s_red[3][tid];
    __syncthreads();
}

// ---------------------------------------------------------------------------
// Persistent kernel: 2 independent groups x 64 blocks x 256 threads.
// Per step: rf-wait -> stage r + finish G -> bar1 -> X -> xf -> M -> rf,
// with the h-part of G(t+1) pre-staged/pre-computed during the M window.
// ---------------------------------------------------------------------------
__global__ __launch_bounds__(256, 1) void k_main(
    const float* __restrict__ W_ih, const float* __restrict__ W_hh,
    const float* __restrict__ W_int, const float* __restrict__ b_int,
    const float* __restrict__ gx, float* __restrict__ hbuf,
    float* __restrict__ rbuf, float* __restrict__ xib,
    float* __restrict__ hr, float* __restrict__ out,
    unsigned* __restrict__ flags, unsigned* __restrict__ go,
    unsigned* __restrict__ xf, unsigned* __restrict__ rf)
{
    const int tid = threadIdx.x;
    const int bi  = blockIdx.x;
    const int g   = bi >> 6;         // group 0/1
    const int bl  = bi & 63;         // block-in-group
    const int bg0 = g * 8;           // first global batch of group

    // ---- LDS (~82 KB) ----
    __shared__ __align__(16) float big_u[13312];  // G: 8x1664 / X: 8x592
    __shared__ __align__(16) float s_xi[3072];    // M: staged xi
    __shared__ float s_part[1024];
    __shared__ float s_tot[256];
    __shared__ float c_s[64];                     // persistent c (8 j x 8 b)
    __shared__ __align__(16) float s_M[5][520];   // persistent M (M-blocks)
    __shared__ float st_u[5], st_p[5], st_L[25], st_wr[10], st_ww[5];
    __shared__ float s_red[4][20];
    __shared__ float s_rb[2], s_wb, s_fg[2], s_ga, s_gw, s_pi[2][3];
    __shared__ float s_wrold[2][5], s_uu[5], s_a[5], s_wwn[5];
    __shared__ float s_pold[5], s_Lnew[25];
    __shared__ float s_zw[5], s_z[2][5], s_fw[2][5], s_bw[2][5];
    __shared__ float s_dotA[11], s_dotB[17], s_wrnew[2][5];

    // ---- init persistent LDS state ----
    if (tid < 64) c_s[tid] = 0.f;
    if (bl < 8) {
        for (int i = tid; i < 5 * 520; i += 256) (&s_M[0][0])[i] = 0.f;
        if (tid < 5)  { st_u[tid] = 0.f; st_p[tid] = 0.f; st_ww[tid] = 0.f; }
        if (tid < 25) st_L[tid] = 0.f;
        if (tid < 10) st_wr[tid] = 0.f;
    }
    __syncthreads();

    // G thread roles
    const int cq = tid & 7;            // j-offset within block
    const int ks = tid >> 3;           // 0..31 k-chunk of 48
    const int jcol = bl * 8 + cq;      // hidden index 0..511
    const int npre = (ks < 10) ? 12 : ((ks == 10) ? 8 : 0);
    // staging roles
    const int b8 = tid >> 5, sg = tid & 31;

    // persistent accumulators: hold pre-computed h-part across step boundary
    float acc[4][8];
#pragma unroll
    for (int g_ = 0; g_ < 4; g_++)
#pragma unroll
        for (int b = 0; b < 8; b++) acc[g_][b] = 0.f;   // h(0)=0 -> pre=0

#pragma unroll 1
    for (int t = 0; t < 128; t++) {
        float*       h_out = hbuf + ((t + 1) & 1) * 8192;

        // ---- wait for r(t): producer flags from the group's 8 M-blocks ----
        if (tid < 8) {
            unsigned v;
            do {
                v = __hip_atomic_load(&rf[(bg0 + tid) * 32], __ATOMIC_RELAXED,
                                      __HIP_MEMORY_SCOPE_AGENT);
                if (v < (unsigned)t) __builtin_amdgcn_s_sleep(4);
            } while (v < (unsigned)t);
        }
        __syncthreads();

        // ================= phase G (post): r-part of gates =================
        float gxv;
        {
            int c = tid & 31, b = tid >> 5;
            int col = (c >> 3) * 512 + bl * 8 + (c & 7);
            gxv = gx[((size_t)t * 16 + bg0 + b) * 2048 + col];
        }
        // stage r-part (8 b x 1024), chunk-52 region [552..1664)
        {
            const float* pr = rbuf + (bg0 + b8) * 1024 + sg * 4;
            f32x4 r0, r1, r2, r3, r4, r5, r6, r7;
            ld8r(r0, r1, r2, r3, r4, r5, r6, r7, pr);
#define STG(kk, D) { int k = (kk); int cc = k / 48; \
                     *(f32x4*)&big_u[b8 * 1664 + cc * 52 + (k - cc * 48)] = D; }
            STG(512 + sg * 4 + 0 * 128, r0)  STG(512 + sg * 4 + 1 * 128, r1)
            STG(512 + sg * 4 + 2 * 128, r2)  STG(512 + sg * 4 + 3 * 128, r3)
            STG(512 + sg * 4 + 4 * 128, r4)  STG(512 + sg * 4 + 5 * 128, r5)
            STG(512 + sg * 4 + 6 * 128, r6)  STG(512 + sg * 4 + 7 * 128, r7)
        }
        __syncthreads();
        // r-part MACs (kg >= 512 -> W_ih)
        for (int i = npre; i < 12; i++) {
            int kg = ks * 48 + i * 4;
            f32x4 w[4];
#pragma unroll
            for (int g_ = 0; g_ < 4; g_++)
                w[g_] = *(const f32x4*)(W_ih + (size_t)(g_ * 512 + jcol) * 1536 + kg);
#pragma unroll
            for (int b = 0; b < 8; b++) {
                f32x4 xv = *(const f32x4*)&big_u[b * 1664 + ks * 52 + i * 4];
#pragma unroll
                for (int g_ = 0; g_ < 4; g_++) {
                    acc[g_][b] = fmaf(w[g_][0], xv[0], acc[g_][b]);
                    acc[g_][b] = fmaf(w[g_][1], xv[1], acc[g_][b]);
                    acc[g_][b] = fmaf(w[g_][2], xv[2], acc[g_][b]);
                    acc[g_][b] = fmaf(w[g_][3], xv[3], acc[g_][b]);
                }
            }
        }
#pragma unroll
        for (int g_ = 0; g_ < 4; g_++)
#pragma unroll
            for (int b = 0; b < 8; b++) {
                float x = acc[g_][b];
                x += __shfl_xor(x, 8, 64);
                x += __shfl_xor(x, 16, 64);
                x += __shfl_xor(x, 32, 64);
                acc[g_][b] = x;
            }
        {
            int wv = tid >> 6;
            if ((tid & 63) < 8) {
#pragma unroll
                for (int g_ = 0; g_ < 4; g_++)
#pragma unroll
                    for (int b = 0; b < 8; b++)
                        s_part[((wv * 4 + g_) * 8 + cq) * 8 + b] = acc[g_][b];
            }
        }
        __syncthreads();
        {
            int c = tid & 31, b = tid >> 5;
            int g_ = c >> 3, jq = c & 7;
            float tot = gxv;
#pragma unroll
            for (int w = 0; w < 4; w++)
                tot += s_part[((w * 4 + g_) * 8 + jq) * 8 + b];
            s_tot[c * 8 + b] = tot;
        }
        __syncthreads();
        if (tid < 64) {
            int jl = tid & 7, b = tid >> 3;
            float gi  = s_tot[(0 * 8 + jl) * 8 + b];
            float gf  = s_tot[(1 * 8 + jl) * 8 + b];
            float gg  = s_tot[(2 * 8 + jl) * 8 + b];
            float go_ = s_tot[(3 * 8 + jl) * 8 + b];
            float cc = sigmf(gf) * c_s[jl * 8 + b] + sigmf(gi) * tanhf(gg);
            float hh = sigmf(go_) * tanhf(cc);
            c_s[jl * 8 + b] = cc;
            int j = bl * 8 + jl;
            int bgl = bg0 + b;
            gst(h_out + bgl * 512 + j, hh);               // coherent
            hr[((size_t)t * 16 + bgl) * 1536 + j] = hh;   // cached sink
            if (t == 127) {
                out[1048576 + bgl * 512 + j] = hh;
                out[1048576 + 8192 + bgl * 512 + j] = cc;
            }
        }
        gsync(flags, go, (unsigned)(t + 1), bi, bl, g, tid);   // h published

        // ================= phase X: xi = h @ W_int + b_int =================
        {
            // stage h_out (8 x 512), chunk-36 rows
            {
                const float* ph = h_out + (bg0 + b8) * 512 + sg * 4;
                f32x4 e0, e1, e2, e3;
                ld4o(e0, e1, e2, e3, ph);
#define STX(j, E) { int k = sg * 4 + (j) * 128; \
                    *(f32x4*)&big_u[b8 * 592 + (k >> 5) * 36 + (k & 31)] = E; }
                STX(0, e0) STX(1, e1) STX(2, e2) STX(3, e3)
#undef STX
            }
            __syncthreads();
            const int ql  = tid & 15;
            const int kcl = tid >> 4;      // 0..15, 32 k each
#pragma unroll 1
            for (int p = 0; p < 3; p++) {
                if (p == 2 && bl >= 33) break;
                int q0 = p * 1024 + bl * 16;          // contiguous 16-col stripe
                int q  = q0 + ql;
                int qc = (q < 2573) ? q : 2572;
                float wxr[32];
#pragma unroll
                for (int i = 0; i < 32; i++)
                    wxr[i] = W_int[(size_t)(kcl * 32 + i) * 2573 + qc];
                float ax[8];
#pragma unroll
                for (int b = 0; b < 8; b++) ax[b] = 0.f;
#pragma unroll
                for (int b = 0; b < 8; b++) {
                    const f32x4* hp = (const f32x4*)&big_u[b * 592 + kcl * 36];
#pragma unroll
                    for (int i4 = 0; i4 < 8; i4++) {
                        f32x4 hv = hp[i4];
                        ax[b] = fmaf(wxr[i4 * 4 + 0], hv[0], ax[b]);
                        ax[b] = fmaf(wxr[i4 * 4 + 1], hv[1], ax[b]);
                        ax[b] = fmaf(wxr[i4 * 4 + 2], hv[2], ax[b]);
                        ax[b] = fmaf(wxr[i4 * 4 + 3], hv[3], ax[b]);
                    }
                }
#pragma unroll
                for (int b = 0; b < 8; b++) {
                    float x = ax[b];
                    x += __shfl_xor(x, 16, 64);
                    x += __shfl_xor(x, 32, 64);
                    ax[b] = x;
                }
                {
                    int wv = tid >> 6;
                    if ((tid & 63) < 16) {
#pragma unroll
                        for (int b = 0; b < 8; b++)
                            s_part[(wv * 16 + ql) * 8 + b] = ax[b];
                    }
                }
                __syncthreads();
                if (tid < 128) {
                    int q_l = tid >> 3, b = tid & 7;
                    int qq = q0 + q_l;
                    if (qq < 2573) {
                        float v = b_int[qq];
#pragma unroll
                        for (int w = 0; w < 4; w++)
                            v += s_part[(w * 16 + q_l) * 8 + b];
                        gst(&xib[(bg0 + b) * 3072 + qq], v);    // coherent
                    }
                }
                __syncthreads();
            }
        }
        // announce xi completion
        __builtin_amdgcn_s_waitcnt(0);
        __syncthreads();
        if (tid == 0)
            __hip_atomic_store(&xf[bi * 32], (unsigned)(t + 1),
                               __ATOMIC_RELAXED, __HIP_MEMORY_SCOPE_AGENT);

        // ================= phase M: memory machinery (bl 0..7) =================
        if (bl < 8) {
            const int bg = bg0 + bl;
            if (tid < GBLK) {
                unsigned v;
                do {
                    v = __hip_atomic_load(&xf[(g * GBLK + tid) * 32], __ATOMIC_RELAXED,
                                          __HIP_MEMORY_SCOPE_AGENT);
                    if (v < (unsigned)(t + 1)) __builtin_amdgcn_s_sleep(2);
                } while (v < (unsigned)(t + 1));
            }
            __syncthreads();
            {
                const float* xs = xib + bg * 3072;
                f32x4 d0, d1, d2;
                cld3(d0, d1, d2,
                     xs + (tid + 0) * 4, xs + (tid + 256) * 4, xs + (tid + 512) * 4);
                *(f32x4*)&s_xi[(tid + 0) * 4]   = d0;
                *(f32x4*)&s_xi[(tid + 256) * 4] = d1;
                *(f32x4*)&s_xi[(tid + 512) * 4] = d2;
            }
            __syncthreads();
            const float* xb = s_xi;

            if (tid == 0) {
                s_wb = oneplusf(xb[1538]);
                s_ga = sigmf(xb[2565]);
                s_gw = sigmf(xb[2566]);
            }
            if (tid == 1 || tid == 2) {
                int rr = tid - 1;
                s_rb[rr] = oneplusf(xb[1024 + rr]);
                s_fg[rr] = sigmf(xb[2563 + rr]);
                float z0 = xb[2567 + rr * 3], z1 = xb[2568 + rr * 3], z2 = xb[2569 + rr * 3];
                float mx = fmaxf(z0, fmaxf(z1, z2));
                float e0 = expf(z0 - mx), e1 = expf(z1 - mx), e2 = expf(z2 - mx);
                float s = e0 + e1 + e2;
                s_pi[rr][0] = e0 / s; s_pi[rr][1] = e1 / s; s_pi[rr][2] = e2 / s;
            }
            if (tid >= 32 && tid < 42) { int i = tid - 32; s_wrold[i / 5][i % 5] = st_wr[i]; }
            if (tid >= 64 && tid < 69) { s_pold[tid - 64] = st_p[tid - 64]; }
            __syncthreads();
            if (tid < 5) {
                float psi = (1.f - s_fg[0] * s_wrold[0][tid]) * (1.f - s_fg[1] * s_wrold[1][tid]);
                float un = (st_u[tid] + st_ww[tid] - st_u[tid] * st_ww[tid]) * psi;
                s_uu[tid] = un; st_u[tid] = un;
            }
            __syncthreads();
            if (tid < 5) {
                float excl = 1.f;
#pragma unroll
                for (int m2 = 0; m2 < 5; m2++) {
                    bool before = (s_uu[m2] < s_uu[tid]) || (s_uu[m2] == s_uu[tid] && m2 < tid);
                    if (before) excl *= s_uu[m2];
                }
                s_a[tid] = (1.f - s_uu[tid]) * excl;
            }
            float accA[11];
#pragma unroll
            for (int i = 0; i < 11; i++) accA[i] = 0.f;
            for (int w = tid; w < 512; w += 256) {
                float wk = xb[1026 + w];
                accA[10] += wk * wk;
#pragma unroll
                for (int n = 0; n < 5; n++) {
                    float m_ = s_M[n][w];
                    accA[n]     += m_ * m_;
                    accA[5 + n] += wk * m_;
                }
            }
            blk_reduce<11>(accA, s_red, s_dotA, tid);
            if (tid < 5) {
                float sim = s_dotA[5 + tid] /
                            ((sqrtf(s_dotA[10]) + EPSC) * (sqrtf(s_dotA[tid]) + EPSC));
                s_zw[tid] = s_wb * sim;
            }
            __syncthreads();
            if (tid < 5) {
                float mx = s_zw[0];
#pragma unroll
                for (int m2 = 1; m2 < 5; m2++) mx = fmaxf(mx, s_zw[m2]);
                float sum = 0.f;
#pragma unroll
                for (int m2 = 0; m2 < 5; m2++) sum += expf(s_zw[m2] - mx);
                float cw = expf(s_zw[tid] - mx) / sum;
                float w_ = s_gw * (s_ga * s_a[tid] + (1.f - s_ga) * cw);
                s_wwn[tid] = w_; st_ww[tid] = w_;
            }
            __syncthreads();
            float accB[17];
#pragma unroll
            for (int i = 0; i < 17; i++) accB[i] = 0.f;
            for (int w = tid; w < 512; w += 256) {
                float ew = sigmf(xb[1539 + w]);
                float vw = xb[2051 + w];
                float rk0 = xb[w], rk1 = xb[512 + w];
                accB[15] += rk0 * rk0; accB[16] += rk1 * rk1;
#pragma unroll
                for (int n = 0; n < 5; n++) {
                    float m_ = s_M[n][w];
                    float mn_ = m_ * (1.f - s_wwn[n] * ew) + s_wwn[n] * vw;
                    s_M[n][w] = mn_;
                    accB[n]      += mn_ * mn_;
                    accB[5 + n]  += rk0 * mn_;
                    accB[10 + n] += rk1 * mn_;
                }
            }
            blk_reduce<17>(accB, s_red, s_dotB, tid);
            if (tid < 25) {
                int i2 = tid / 5, j2 = tid % 5;
                float Ln = (i2 == j2) ? 0.f
                         : (1.f - s_wwn[i2] - s_wwn[j2]) * st_L[tid] + s_wwn[i2] * s_pold[j2];
                s_Lnew[tid] = Ln; st_L[tid] = Ln;
            }
            __syncthreads();
            if (tid < 5) {
                float wsum = s_wwn[0] + s_wwn[1] + s_wwn[2] + s_wwn[3] + s_wwn[4];
                st_p[tid] = (1.f - wsum) * s_pold[tid] + s_wwn[tid];
            }
            if (tid < 10) {
                int rr = tid / 5, ii = tid % 5;
                float fw = 0.f, bw = 0.f;
#pragma unroll
                for (int j2 = 0; j2 < 5; j2++) {
                    fw += s_Lnew[ii * 5 + j2] * s_wrold[rr][j2];
                    bw += s_Lnew[j2 * 5 + ii] * s_wrold[rr][j2];
                }
                s_fw[rr][ii] = fw; s_bw[rr][ii] = bw;
                float sim = s_dotB[5 + rr * 5 + ii] /
                            ((sqrtf(s_dotB[15 + rr]) + EPSC) * (sqrtf(s_dotB[ii]) + EPSC));
                s_z[rr][ii] = s_rb[rr] * sim;
            }
            __syncthreads();
            if (tid < 10) {
                int rr = tid / 5, ii = tid % 5;
                float mx = s_z[rr][0];
#pragma unroll
                for (int m2 = 1; m2 < 5; m2++) mx = fmaxf(mx, s_z[rr][m2]);
                float sum = 0.f;
#pragma unroll
                for (int m2 = 0; m2 < 5; m2++) sum += expf(s_z[rr][m2] - mx);
                float cr = expf(s_z[rr][ii] - mx) / sum;
                float wn = s_pi[rr][0] * s_bw[rr][ii] + s_pi[rr][1] * cr + s_pi[rr][2] * s_fw[rr][ii];
                s_wrnew[rr][ii] = wn; st_wr[rr * 5 + ii] = wn;
            }
            __syncthreads();
            for (int idx = tid; idx < 1024; idx += 256) {
                int rr = idx >> 9, w = idx & 511;
                float rv = 0.f;
#pragma unroll
                for (int n = 0; n < 5; n++) rv += s_wrnew[rr][n] * s_M[n][w];
                gst(&rbuf[bg * 1024 + idx], rv);        // coherent
                hr[((size_t)t * 16 + bg) * 1536 + 512 + idx] = rv;
            }
            __builtin_amdgcn_s_waitcnt(0);
            __syncthreads();
            if (tid == 0)
                __hip_atomic_store(&rf[bg * 32], (unsigned)(t + 1),
                                   __ATOMIC_RELAXED, __HIP_MEMORY_SCOPE_AGENT);
        }

        // ===== pre-phase for t+1: stage h-part + compute h-part gates =====
        // (overlaps the M window for non-M blocks; M-blocks do it post-rf)
#pragma unroll
        for (int g_ = 0; g_ < 4; g_++)
#pragma unroll
            for (int b = 0; b < 8; b++) acc[g_][b] = 0.f;
        if (t < 127) {
            {
                const float* ph = h_out + (bg0 + b8) * 512 + sg * 4;
                f32x4 e0, e1, e2, e3;
                ld4o(e0, e1, e2, e3, ph);
                STG(sg * 4 + 0 * 128, e0)  STG(sg * 4 + 1 * 128, e1)
                STG(sg * 4 + 2 * 128, e2)  STG(sg * 4 + 3 * 128, e3)
#undef STG
            }
            __syncthreads();
            for (int i = 0; i < npre; i++) {
                int kg = ks * 48 + i * 4;
                f32x4 w[4];
#pragma unroll
                for (int g_ = 0; g_ < 4; g_++)
                    w[g_] = *(const f32x4*)(W_hh + (size_t)(g_ * 512 + jcol) * 512 + kg);
#pragma unroll
                for (int b = 0; b < 8; b++) {
                    f32x4 xv = *(const f32x4*)&big_u[b * 1664 + ks * 52 + i * 4];
#pragma unroll
                    for (int g_ = 0; g_ < 4; g_++) {
                        acc[g_][b] = fmaf(w[g_][0], xv[0], acc[g_][b]);
                        acc[g_][b] = fmaf(w[g_][1], xv[1], acc[g_][b]);
                        acc[g_][b] = fmaf(w[g_][2], xv[2], acc[g_][b]);
                        acc[g_][b] = fmaf(w[g_][3], xv[3], acc[g_][b]);
                    }
                }
            }
        }
    }
}

// ---------------------------------------------------------------------------
// Prologue: gates_x[tok][col] = b_lstm[col] + sum_{k<512} emb[src_tok,k]*W_ih[col,k]
// ---------------------------------------------------------------------------
__global__ __launch_bounds__(256) void k_embgx(
    const int* __restrict__ src, const float* __restrict__ emb,
    const float* __restrict__ W_ih, const float* __restrict__ b_lstm,
    float* __restrict__ gx)
{
    __shared__ __align__(16) float As[16][68];
    __shared__ __align__(16) float Bs[16][68];
    const int tid = threadIdx.x;
    const int bm = blockIdx.x, bn = blockIdx.y;
    const int tm = tid >> 4, tn = tid & 15;
    float acc[4][4] = {};
    for (int k0 = 0; k0 < 512; k0 += 16) {
#pragma unroll
        for (int i = 0; i < 4; i++) {
            int idx = tid + 256 * i;
            int m = idx >> 4, kk = idx & 15;
            int tok = bm * 64 + m;
            int row = src[(tok & 15) * 128 + (tok >> 4)];
            As[kk][m] = emb[(size_t)row * 512 + k0 + kk];
        }
#pragma unroll
        for (int i = 0; i < 4; i++) {
            int idx = tid + 256 * i;
            int n = idx >> 4, kk = idx & 15;
            Bs[kk][n] = W_ih[(size_t)(bn * 64 + n) * 1536 + k0 + kk];
        }
        __syncthreads();
#pragma unroll
        for (int kk = 0; kk < 16; kk++) {
            float4 av = *(const float4*)&As[kk][tm * 4];
            float4 bv = *(const float4*)&Bs[kk][tn * 4];
            float a[4] = {av.x, av.y, av.z, av.w};
            float b[4] = {bv.x, bv.y, bv.z, bv.w};
#pragma unroll
            for (int i = 0; i < 4; i++)
#pragma unroll
                for (int j = 0; j < 4; j++) acc[i][j] = fmaf(a[i], b[j], acc[i][j]);
        }
        __syncthreads();
    }
#pragma unroll
    for (int i = 0; i < 4; i++) {
        int tok = bm * 64 + tm * 4 + i;
#pragma unroll
        for (int j = 0; j < 4; j++) {
            int col = bn * 64 + tn * 4 + j;
            gx[(size_t)tok * 2048 + col] = acc[i][j] + b_lstm[col];
        }
    }
}

// ---------------------------------------------------------------------------
// Epilogue: out[b,s,q] = b_out[q] + sum_k hr[s,b,k]*W_out[k,q]
// ---------------------------------------------------------------------------
__global__ __launch_bounds__(256) void k_out(
    const float* __restrict__ hr, const float* __restrict__ W_out,
    const float* __restrict__ b_out, float* __restrict__ out)
{
    __shared__ __align__(16) float As[16][68];
    __shared__ __align__(16) float Bs[16][68];
    const int tid = threadIdx.x;
    const int bm = blockIdx.x, bn = blockIdx.y;
    const int tm = tid >> 4, tn = tid & 15;
    float acc[4][4] = {};
    for (int k0 = 0; k0 < 1536; k0 += 16) {
#pragma unroll
        for (int i = 0; i < 4; i++) {
            int idx = tid + 256 * i;
            int m = idx >> 4, kk = idx & 15;
            As[kk][m] = hr[(size_t)(bm * 64 + m) * 1536 + k0 + kk];
        }
#pragma unroll
        for (int i = 0; i < 4; i++) {
            int idx = tid + 256 * i;
            int kk = idx >> 6, n = idx & 63;
            Bs[kk][n] = W_out[(size_t)(k0 + kk) * 512 + bn * 64 + n];
        }
        __syncthreads();
#pragma unroll
        for (int kk = 0; kk < 16; kk++) {
            float4 av = *(const float4*)&As[kk][tm * 4];
            float4 bv = *(const float4*)&Bs[kk][tn * 4];
            float a[4] = {av.x, av.y, av.z, av.w};
            float b[4] = {bv.x, bv.y, bv.z, bv.w};
#pragma unroll
            for (int i = 0; i < 4; i++)
#pragma unroll
                for (int j = 0; j < 4; j++) acc[i][j] = fmaf(a[i], b[j], acc[i][j]);
        }
        __syncthreads();
    }
#pragma unroll
    for (int i = 0; i < 4; i++) {
        int tok = bm * 64 + tm * 4 + i;
        int b_ = tok & 15, s_ = tok >> 4;
#pragma unroll
        for (int j = 0; j < 4; j++) {
            int qn = bn * 64 + tn * 4 + j;
            out[(size_t)((b_ << 7) + s_) * 512 + qn] = acc[i][j] + b_out[qn];
        }
    }
}

extern "C" void kernel_launch(void* const* d_in, const int* in_sizes, int n_in,
                              void* d_out, int out_size, void* d_ws, size_t ws_size,
                              hipStream_t stream)
{
    const int*   src    = (const int*)d_in[0];
    const float* emb    = (const float*)d_in[2];
    const float* W_ih   = (const float*)d_in[3];
    const float* W_hh   = (const float*)d_in[4];
    const float* b_lstm = (const float*)d_in[5];
    const float* W_int  = (const float*)d_in[6];
    const float* b_int  = (const float*)d_in[7];
    const float* W_out  = (const float*)d_in[8];
    const float* b_out  = (const float*)d_in[9];

    float* ws  = (float*)d_ws;
    float* out = (float*)d_out;

    float*    hbuf  = ws + OFF_H;
    float*    rbuf  = ws + OFF_R;
    unsigned* flags = (unsigned*)(ws + OFF_FLAGS);
    unsigned* go    = (unsigned*)(ws + OFF_GO);
    unsigned* xf    = (unsigned*)(ws + OFF_XF);
    unsigned* rf    = (unsigned*)(ws + OFF_RF);
    float*    xib   = ws + OFF_XI;
    float*    gx    = ws + OFF_GX;
    float*    hrb   = ws + OFF_HR;

    // zero recurrent state + all sync flags (deterministic across replays)
    hipMemsetAsync(ws, 0, STATE_END * sizeof(float), stream);

    // prologue: token-parallel x-part of gates (+ bias)
    k_embgx<<<dim3(32, 32), 256, 0, stream>>>(src, emb, W_ih, b_lstm, gx);

    // main loop: 2 independent 64-block groups (batches 0-7 / 8-15)
    k_main<<<dim3(NBLK), dim3(256), 0, stream>>>(
        W_ih, W_hh, W_int, b_int, gx, hbuf, rbuf, xib, hrb, out,
        flags, go, xf, rf);

    // epilogue: token-parallel output projection
    k_out<<<dim3(32, 8), 256, 0, stream>>>(hrb, W_out, b_out, out);
}

// Round 13
// 4143.456 us; speedup vs baseline: 1.1779x; 1.1779x over previous
//
#include <hip/hip_runtime.h>
#include <math.h>

// B=16, S=128, H=512, V=50000, N=5, R=2, Wd=512, XI=2573
#define EPSC 1e-6f
#define NBLK 128
#define GBLK 64     // blocks per group; 2 independent groups of 8 batches

// ws layout (float offsets)
#define OFF_H     0u         // hbuf[2][16][512]
#define OFF_R     16384u     // r[16][1024]
#define OFF_FLAGS 32768u     // bar1 arrival flags: 128 x 32 u32
#define OFF_GO    36864u     // bar1 go lines:      128 x 32 u32
#define OFF_XF    40960u     // xi pass-B flags:    128 x 32 u32
#define OFF_XFA   45056u     // xi pass-A flags:    128 x 32 u32
#define OFF_RF    49152u     // r-producer flags:   16 x 32 u32 (+pad)
#define STATE_END 50176u
#define OFF_XI    50176u     // xi[16][3072] (padded rows)
#define OFF_GX    99328u     // gates_x[128][16][2048]
#define OFF_HR    4293632u   // hr[128][16][1536]
// end 7439360 floats = 29.76 MB

typedef float f32x4 __attribute__((ext_vector_type(4)));

__device__ __forceinline__ float sigmf(float x) { return 1.0f / (1.0f + expf(-x)); }
__device__ __forceinline__ float oneplusf(float x) {
    return 1.0f + fmaxf(x, 0.0f) + log1pf(expf(-fabsf(x)));
}

// coherent scalar store (agent scope, bypasses L1/L2) — proven r3-r12
__device__ __forceinline__ void gst(float* p, float v) {
    __hip_atomic_store((unsigned*)p, __float_as_uint(v),
                       __ATOMIC_RELAXED, __HIP_MEMORY_SCOPE_AGENT);
}

// 8 coherent dwordx4 loads, one base, offsets 0..3584 step 512 B (r-part).
__device__ __forceinline__ void ld8r(
    f32x4& r0, f32x4& r1, f32x4& r2, f32x4& r3,
    f32x4& r4, f32x4& r5, f32x4& r6, f32x4& r7, const float* pr)
{
    asm volatile(
        "global_load_dwordx4 %0, %8, off sc0 sc1\n\t"
        "global_load_dwordx4 %1, %8, off offset:512 sc0 sc1\n\t"
        "global_load_dwordx4 %2, %8, off offset:1024 sc0 sc1\n\t"
        "global_load_dwordx4 %3, %8, off offset:1536 sc0 sc1\n\t"
        "global_load_dwordx4 %4, %8, off offset:2048 sc0 sc1\n\t"
        "global_load_dwordx4 %5, %8, off offset:2560 sc0 sc1\n\t"
        "global_load_dwordx4 %6, %8, off offset:3072 sc0 sc1\n\t"
        "global_load_dwordx4 %7, %8, off offset:3584 sc0 sc1\n\t"
        "s_waitcnt vmcnt(0)"
        : "=&v"(r0), "=&v"(r1), "=&v"(r2), "=&v"(r3),
          "=&v"(r4), "=&v"(r5), "=&v"(r6), "=&v"(r7)
        : "v"(pr)
        : "memory");
}

// 4 coherent dwordx4 loads from one base, offsets 0/512/1024/1536 B.
__device__ __forceinline__ void ld4o(
    f32x4& d0, f32x4& d1, f32x4& d2, f32x4& d3, const float* p)
{
    asm volatile(
        "global_load_dwordx4 %0, %4, off sc0 sc1\n\t"
        "global_load_dwordx4 %1, %4, off offset:512 sc0 sc1\n\t"
        "global_load_dwordx4 %2, %4, off offset:1024 sc0 sc1\n\t"
        "global_load_dwordx4 %3, %4, off offset:1536 sc0 sc1\n\t"
        "s_waitcnt vmcnt(0)"
        : "=&v"(d0), "=&v"(d1), "=&v"(d2), "=&v"(d3)
        : "v"(p)
        : "memory");
}

__device__ __forceinline__ void cld2(
    f32x4& d0, f32x4& d1, const float* p0, const float* p1)
{
    asm volatile(
        "global_load_dwordx4 %0, %2, off sc0 sc1\n\t"
        "global_load_dwordx4 %1, %3, off sc0 sc1\n\t"
        "s_waitcnt vmcnt(0)"
        : "=&v"(d0), "=&v"(d1)
        : "v"(p0), "v"(p1)
        : "memory");
}

__device__ __forceinline__ void cld1(f32x4& d0, const float* p0)
{
    asm volatile(
        "global_load_dwordx4 %0, %1, off sc0 sc1\n\t"
        "s_waitcnt vmcnt(0)"
        : "=&v"(d0)
        : "v"(p0)
        : "memory");
}

// Fence-free 2-hop mailbox barrier, PER GROUP (1 poller per line).
__device__ __forceinline__ void gsync(unsigned* flags, unsigned* go, unsigned gen,
                                      int bi, int bl, int g, int tid)
{
    __builtin_amdgcn_s_waitcnt(0);   // drain this wave's payload stores
    __syncthreads();
    if (tid == 0)
        __hip_atomic_store(&flags[bi * 32], gen, __ATOMIC_RELAXED, __HIP_MEMORY_SCOPE_AGENT);
    if (bl == 0) {
        if (tid < GBLK) {
            unsigned v;
            do {
                v = __hip_atomic_load(&flags[(g * GBLK + tid) * 32], __ATOMIC_RELAXED,
                                      __HIP_MEMORY_SCOPE_AGENT);
                if (v < gen) __builtin_amdgcn_s_sleep(1);
            } while (v < gen);
        }
        __syncthreads();
        if (tid < GBLK)
            __hip_atomic_store(&go[(g * GBLK + tid) * 32], gen, __ATOMIC_RELAXED,
                               __HIP_MEMORY_SCOPE_AGENT);
    }
    if (tid == 0) {
        unsigned v;
        do {
            v = __hip_atomic_load(&go[bi * 32], __ATOMIC_RELAXED, __HIP_MEMORY_SCOPE_AGENT);
            if (v < gen) __builtin_amdgcn_s_sleep(1);
        } while (v < gen);
    }
    __syncthreads();
}

template <int K>
__device__ __forceinline__ void blk_reduce(float* v, float (*s_red)[20],
                                           float* outp, int tid)
{
#pragma unroll
    for (int i = 0; i < K; i++) {
        float x = v[i];
        for (int o = 32; o > 0; o >>= 1) x += __shfl_down(x, o, 64);
        if ((tid & 63) == 0) s_red[tid >> 6][i] = x;
    }
    __syncthreads();
    if (tid < K) outp[tid] = s_red[0][tid] + s_red[1][tid] + s_red[2][tid] + s_red[3][tid];
    __syncthreads();
}

// ---------------------------------------------------------------------------
// Persistent kernel: 2 independent groups x 64 blocks x 256 threads.
// Per step: h-stage | rf-wait -> r-stage + G -> bar1 -> X(pA) -> xfA ->
//           X(pB) -> xf ; M overlaps pB after xfA, rk-tail after xf -> rf.
// ---------------------------------------------------------------------------
__global__ __launch_bounds__(256, 1) void k_main(
    const float* __restrict__ W_ih, const float* __restrict__ W_hh,
    const float* __restrict__ W_int, const float* __restrict__ b_int,
    const float* __restrict__ gx, float* __restrict__ hbuf,
    float* __restrict__ rbuf, float* __restrict__ xib,
    float* __restrict__ hr, float* __restrict__ out,
    unsigned* __restrict__ flags, unsigned* __restrict__ go,
    unsigned* __restrict__ xf, unsigned* __restrict__ xfa,
    unsigned* __restrict__ rf)
{
    const int tid = threadIdx.x;
    const int bi  = blockIdx.x;
    const int g   = bi >> 6;         // group 0/1
    const int bl  = bi & 63;         // block-in-group
    const int bg0 = g * 8;           // first global batch of group

    // ---- LDS (~82 KB) ----
    __shared__ __align__(16) float big_u[13312];  // G: 8x1664 / X: 8x592
    __shared__ __align__(16) float s_xi[3072];    // M: xi upper[2048] + lower[1024]
    __shared__ float s_part[1024];
    __shared__ float s_tot[256];
    __shared__ float c_s[64];                     // persistent c (8 j x 8 b)
    __shared__ __align__(16) float s_M[5][520];   // persistent M (M-blocks)
    __shared__ float st_u[5], st_p[5], st_L[25], st_wr[10], st_ww[5];
    __shared__ float s_red[4][20];
    __shared__ float s_rb[2], s_wb, s_fg[2], s_ga, s_gw, s_pi[2][3];
    __shared__ float s_wrold[2][5], s_uu[5], s_a[5], s_wwn[5];
    __shared__ float s_pold[5], s_Lnew[25];
    __shared__ float s_zw[5], s_z[2][5], s_fw[2][5], s_bw[2][5];
    __shared__ float s_dotA[11], s_dotB[5], s_dotR[12], s_wrnew[2][5];

    // ---- init persistent LDS state ----
    if (tid < 64) c_s[tid] = 0.f;
    if (bl < 8) {
        for (int i = tid; i < 5 * 520; i += 256) (&s_M[0][0])[i] = 0.f;
        if (tid < 5)  { st_u[tid] = 0.f; st_p[tid] = 0.f; st_ww[tid] = 0.f; }
        if (tid < 25) st_L[tid] = 0.f;
        if (tid < 10) st_wr[tid] = 0.f;
    }
    __syncthreads();

    // thread roles
    const int cq = tid & 7;            // j-offset within block
    const int ks = tid >> 3;           // 0..31 k-chunk of 48
    const int jcol = bl * 8 + cq;      // hidden index 0..511
    const int b8 = tid >> 5, sg = tid & 31;

#pragma unroll 1
    for (int t = 0; t < 128; t++) {
        const float* h_in  = hbuf + (t & 1) * 8192;
        float*       h_out = hbuf + ((t + 1) & 1) * 8192;

#define STG(kk, D) { int k = (kk); int cc = k / 48; \
                     *(f32x4*)&big_u[b8 * 1664 + cc * 52 + (k - cc * 48)] = D; }
        // ---- stage h-part NOW (published at bar1 of step t-1); hides under rf-wait
        {
            const float* ph = h_in + (bg0 + b8) * 512 + sg * 4;
            f32x4 e0, e1, e2, e3;
            ld4o(e0, e1, e2, e3, ph);
            STG(sg * 4 + 0 * 128, e0)  STG(sg * 4 + 1 * 128, e1)
            STG(sg * 4 + 2 * 128, e2)  STG(sg * 4 + 3 * 128, e3)
        }
        // gx prefetch (cached, independent)
        float gxv;
        {
            int c = tid & 31, b = tid >> 5;
            int col = (c >> 3) * 512 + bl * 8 + (c & 7);
            gxv = gx[((size_t)t * 16 + bg0 + b) * 2048 + col];
        }
        // ---- wait for r(t) ----
        if (tid < 8) {
            unsigned v;
            do {
                v = __hip_atomic_load(&rf[(bg0 + tid) * 32], __ATOMIC_RELAXED,
                                      __HIP_MEMORY_SCOPE_AGENT);
                if (v < (unsigned)t) __builtin_amdgcn_s_sleep(4);
            } while (v < (unsigned)t);
        }
        __syncthreads();

        // ================= phase G: r-stage + full gate MACs =================
        {
            const float* pr = rbuf + (bg0 + b8) * 1024 + sg * 4;
            f32x4 r0, r1, r2, r3, r4, r5, r6, r7;
            ld8r(r0, r1, r2, r3, r4, r5, r6, r7, pr);
            STG(512 + sg * 4 + 0 * 128, r0)  STG(512 + sg * 4 + 1 * 128, r1)
            STG(512 + sg * 4 + 2 * 128, r2)  STG(512 + sg * 4 + 3 * 128, r3)
            STG(512 + sg * 4 + 4 * 128, r4)  STG(512 + sg * 4 + 5 * 128, r5)
            STG(512 + sg * 4 + 6 * 128, r6)  STG(512 + sg * 4 + 7 * 128, r7)
        }
#undef STG
        __syncthreads();

        float acc[4][8];
#pragma unroll
        for (int g_ = 0; g_ < 4; g_++)
#pragma unroll
            for (int b = 0; b < 8; b++) acc[g_][b] = 0.f;
#pragma unroll
        for (int i = 0; i < 12; i++) {
            int kg = ks * 48 + i * 4;
            f32x4 w[4];
#pragma unroll
            for (int g_ = 0; g_ < 4; g_++) {
                const float* wp = (kg < 512)
                    ? W_hh + (size_t)(g_ * 512 + jcol) * 512 + kg
                    : W_ih + (size_t)(g_ * 512 + jcol) * 1536 + kg;
                w[g_] = *(const f32x4*)wp;
            }
#pragma unroll
            for (int b = 0; b < 8; b++) {
                f32x4 xv = *(const f32x4*)&big_u[b * 1664 + ks * 52 + i * 4];
#pragma unroll
                for (int g_ = 0; g_ < 4; g_++) {
                    acc[g_][b] = fmaf(w[g_][0], xv[0], acc[g_][b]);
                    acc[g_][b] = fmaf(w[g_][1], xv[1], acc[g_][b]);
                    acc[g_][b] = fmaf(w[g_][2], xv[2], acc[g_][b]);
                    acc[g_][b] = fmaf(w[g_][3], xv[3], acc[g_][b]);
                }
            }
        }
#pragma unroll
        for (int g_ = 0; g_ < 4; g_++)
#pragma unroll
            for (int b = 0; b < 8; b++) {
                float x = acc[g_][b];
                x += __shfl_xor(x, 8, 64);
                x += __shfl_xor(x, 16, 64);
                x += __shfl_xor(x, 32, 64);
                acc[g_][b] = x;
            }
        {
            int wv = tid >> 6;
            if ((tid & 63) < 8) {
#pragma unroll
                for (int g_ = 0; g_ < 4; g_++)
#pragma unroll
                    for (int b = 0; b < 8; b++)
                        s_part[((wv * 4 + g_) * 8 + cq) * 8 + b] = acc[g_][b];
            }
        }
        __syncthreads();
        {
            int c = tid & 31, b = tid >> 5;
            int g_ = c >> 3, jq = c & 7;
            float tot = gxv;
#pragma unroll
            for (int w = 0; w < 4; w++)
                tot += s_part[((w * 4 + g_) * 8 + jq) * 8 + b];
            s_tot[c * 8 + b] = tot;
        }
        __syncthreads();
        if (tid < 64) {
            int jl = tid & 7, b = tid >> 3;
            float gi  = s_tot[(0 * 8 + jl) * 8 + b];
            float gf  = s_tot[(1 * 8 + jl) * 8 + b];
            float gg  = s_tot[(2 * 8 + jl) * 8 + b];
            float go_ = s_tot[(3 * 8 + jl) * 8 + b];
            float cc = sigmf(gf) * c_s[jl * 8 + b] + sigmf(gi) * tanhf(gg);
            float hh = sigmf(go_) * tanhf(cc);
            c_s[jl * 8 + b] = cc;
            int j = bl * 8 + jl;
            int bgl = bg0 + b;
            gst(h_out + bgl * 512 + j, hh);               // coherent
            hr[((size_t)t * 16 + bgl) * 1536 + j] = hh;   // cached sink
            if (t == 127) {
                out[1048576 + bgl * 512 + j] = hh;
                out[1048576 + 8192 + bgl * 512 + j] = cc;
            }
        }
        gsync(flags, go, (unsigned)(t + 1), bi, bl, g, tid);   // h published

        // ================= phase X: xi = h @ W_int + b_int =================
        {
            // stage h_out (8 x 512), chunk-36 rows
            {
                const float* ph = h_out + (bg0 + b8) * 512 + sg * 4;
                f32x4 e0, e1, e2, e3;
                ld4o(e0, e1, e2, e3, ph);
#define STX(j, E) { int k = sg * 4 + (j) * 128; \
                    *(f32x4*)&big_u[b8 * 592 + (k >> 5) * 36 + (k & 31)] = E; }
                STX(0, e0) STX(1, e1) STX(2, e2) STX(3, e3)
#undef STX
            }
            __syncthreads();
            const int ql  = tid & 15;
            const int kcl = tid >> 4;      // 0..15, 32 k each
            // pass order: p0=cols 1024-2047, p1=cols 2048-2572 (bl<33),
            //             [post xfA], p2=cols 0-1023
#pragma unroll 1
            for (int p = 0; p < 3; p++) {
                if (p == 2) {
                    // all control/e/v cols written -> announce pass A
                    __builtin_amdgcn_s_waitcnt(0);
                    __syncthreads();
                    if (tid == 0)
                        __hip_atomic_store(&xfa[bi * 32], (unsigned)(t + 1),
                                           __ATOMIC_RELAXED, __HIP_MEMORY_SCOPE_AGENT);
                }
                if (p == 1 && bl >= 33) continue;
                int q0 = (p == 0) ? 1024 + bl * 16
                       : (p == 1) ? 2048 + bl * 16
                                  : bl * 16;
                int q  = q0 + ql;
                int qc = (q < 2573) ? q : 2572;
                float wxr[32];
#pragma unroll
                for (int i = 0; i < 32; i++)
                    wxr[i] = W_int[(size_t)(kcl * 32 + i) * 2573 + qc];
                float ax[8];
#pragma unroll
                for (int b = 0; b < 8; b++) ax[b] = 0.f;
#pragma unroll
                for (int b = 0; b < 8; b++) {
                    const f32x4* hp = (const f32x4*)&big_u[b * 592 + kcl * 36];
#pragma unroll
                    for (int i4 = 0; i4 < 8; i4++) {
                        f32x4 hv = hp[i4];
                        ax[b] = fmaf(wxr[i4 * 4 + 0], hv[0], ax[b]);
                        ax[b] = fmaf(wxr[i4 * 4 + 1], hv[1], ax[b]);
                        ax[b] = fmaf(wxr[i4 * 4 + 2], hv[2], ax[b]);
                        ax[b] = fmaf(wxr[i4 * 4 + 3], hv[3], ax[b]);
                    }
                }
#pragma unroll
                for (int b = 0; b < 8; b++) {
                    float x = ax[b];
                    x += __shfl_xor(x, 16, 64);
                    x += __shfl_xor(x, 32, 64);
                    ax[b] = x;
                }
                {
                    int wv = tid >> 6;
                    if ((tid & 63) < 16) {
#pragma unroll
                        for (int b = 0; b < 8; b++)
                            s_part[(wv * 16 + ql) * 8 + b] = ax[b];
                    }
                }
                __syncthreads();
                if (tid < 128) {
                    int q_l = tid >> 3, b = tid & 7;
                    int qq = q0 + q_l;
                    if (qq < 2573) {
                        float v = b_int[qq];
#pragma unroll
                        for (int w = 0; w < 4; w++)
                            v += s_part[(w * 16 + q_l) * 8 + b];
                        gst(&xib[(bg0 + b) * 3072 + qq], v);    // coherent
                    }
                }
                __syncthreads();
            }
        }
        // announce pass B (rk cols)
        __builtin_amdgcn_s_waitcnt(0);
        __syncthreads();
        if (tid == 0)
            __hip_atomic_store(&xf[bi * 32], (unsigned)(t + 1),
                               __ATOMIC_RELAXED, __HIP_MEMORY_SCOPE_AGENT);

        // ================= phase M: memory machinery (bl 0..7) =================
        if (bl < 8) {
            const int bg = bg0 + bl;
            // ---- first half: starts after pass A (overlaps others' pass B) ----
            if (tid < GBLK) {
                unsigned v;
                do {
                    v = __hip_atomic_load(&xfa[(g * GBLK + tid) * 32], __ATOMIC_RELAXED,
                                          __HIP_MEMORY_SCOPE_AGENT);
                    if (v < (unsigned)(t + 1)) __builtin_amdgcn_s_sleep(2);
                } while (v < (unsigned)(t + 1));
            }
            __syncthreads();
            {   // stage xi cols 1024..3071 -> s_xi[0..2048)
                const float* xs = xib + bg * 3072 + 1024;
                f32x4 d0, d1;
                cld2(d0, d1, xs + tid * 4, xs + 1024 + tid * 4);
                *(f32x4*)&s_xi[tid * 4]        = d0;
                *(f32x4*)&s_xi[1024 + tid * 4] = d1;
            }
            __syncthreads();
            const float* xU = s_xi;   // xU[i] = xi[1024+i]

            if (tid == 0) {
                s_wb = oneplusf(xU[514]);     // 1538
                s_ga = sigmf(xU[1541]);       // 2565
                s_gw = sigmf(xU[1542]);       // 2566
            }
            if (tid == 1 || tid == 2) {
                int rr = tid - 1;
                s_rb[rr] = oneplusf(xU[rr]);          // 1024+rr
                s_fg[rr] = sigmf(xU[1539 + rr]);      // 2563+rr
                float z0 = xU[1543 + rr * 3], z1 = xU[1544 + rr * 3], z2 = xU[1545 + rr * 3];
                float mx = fmaxf(z0, fmaxf(z1, z2));
                float e0 = expf(z0 - mx), e1 = expf(z1 - mx), e2 = expf(z2 - mx);
                float s = e0 + e1 + e2;
                s_pi[rr][0] = e0 / s; s_pi[rr][1] = e1 / s; s_pi[rr][2] = e2 / s;
            }
            if (tid >= 32 && tid < 42) { int i = tid - 32; s_wrold[i / 5][i % 5] = st_wr[i]; }
            if (tid >= 64 && tid < 69) { s_pold[tid - 64] = st_p[tid - 64]; }
            __syncthreads();
            if (tid < 5) {
                float psi = (1.f - s_fg[0] * s_wrold[0][tid]) * (1.f - s_fg[1] * s_wrold[1][tid]);
                float un = (st_u[tid] + st_ww[tid] - st_u[tid] * st_ww[tid]) * psi;
                s_uu[tid] = un; st_u[tid] = un;
            }
            __syncthreads();
            if (tid < 5) {
                float excl = 1.f;
#pragma unroll
                for (int m2 = 0; m2 < 5; m2++) {
                    bool before = (s_uu[m2] < s_uu[tid]) || (s_uu[m2] == s_uu[tid] && m2 < tid);
                    if (before) excl *= s_uu[m2];
                }
                s_a[tid] = (1.f - s_uu[tid]) * excl;
            }
            float accA[11];
#pragma unroll
            for (int i = 0; i < 11; i++) accA[i] = 0.f;
            for (int w = tid; w < 512; w += 256) {
                float wk = xU[2 + w];                 // 1026+w
                accA[10] += wk * wk;
#pragma unroll
                for (int n = 0; n < 5; n++) {
                    float m_ = s_M[n][w];
                    accA[n]     += m_ * m_;
                    accA[5 + n] += wk * m_;
                }
            }
            blk_reduce<11>(accA, s_red, s_dotA, tid);
            if (tid < 5) {
                float sim = s_dotA[5 + tid] /
                            ((sqrtf(s_dotA[10]) + EPSC) * (sqrtf(s_dotA[tid]) + EPSC));
                s_zw[tid] = s_wb * sim;
            }
            __syncthreads();
            if (tid < 5) {
                float mx = s_zw[0];
#pragma unroll
                for (int m2 = 1; m2 < 5; m2++) mx = fmaxf(mx, s_zw[m2]);
                float sum = 0.f;
#pragma unroll
                for (int m2 = 0; m2 < 5; m2++) sum += expf(s_zw[m2] - mx);
                float cw = expf(s_zw[tid] - mx) / sum;
                float w_ = s_gw * (s_ga * s_a[tid] + (1.f - s_ga) * cw);
                s_wwn[tid] = w_; st_ww[tid] = w_;
            }
            __syncthreads();
            // memory write + mn-norms (e,v from pass A)
            float accN[5];
#pragma unroll
            for (int i = 0; i < 5; i++) accN[i] = 0.f;
            for (int w = tid; w < 512; w += 256) {
                float ew = sigmf(xU[515 + w]);        // 1539+w
                float vw = xU[1027 + w];              // 2051+w
#pragma unroll
                for (int n = 0; n < 5; n++) {
                    float m_ = s_M[n][w];
                    float mn_ = m_ * (1.f - s_wwn[n] * ew) + s_wwn[n] * vw;
                    s_M[n][w] = mn_;
                    accN[n] += mn_ * mn_;
                }
            }
            blk_reduce<5>(accN, s_red, s_dotB, tid);
            if (tid < 25) {
                int i2 = tid / 5, j2 = tid % 5;
                float Ln = (i2 == j2) ? 0.f
                         : (1.f - s_wwn[i2] - s_wwn[j2]) * st_L[tid] + s_wwn[i2] * s_pold[j2];
                s_Lnew[tid] = Ln; st_L[tid] = Ln;
            }
            __syncthreads();
            if (tid < 5) {
                float wsum = s_wwn[0] + s_wwn[1] + s_wwn[2] + s_wwn[3] + s_wwn[4];
                st_p[tid] = (1.f - wsum) * s_pold[tid] + s_wwn[tid];
            }
            if (tid < 10) {
                int rr = tid / 5, ii = tid % 5;
                float fw = 0.f, bw = 0.f;
#pragma unroll
                for (int j2 = 0; j2 < 5; j2++) {
                    fw += s_Lnew[ii * 5 + j2] * s_wrold[rr][j2];
                    bw += s_Lnew[j2 * 5 + ii] * s_wrold[rr][j2];
                }
                s_fw[rr][ii] = fw; s_bw[rr][ii] = bw;
            }
            __syncthreads();

            // ---- tail: needs rk (pass B) ----
            if (tid < GBLK) {
                unsigned v;
                do {
                    v = __hip_atomic_load(&xf[(g * GBLK + tid) * 32], __ATOMIC_RELAXED,
                                          __HIP_MEMORY_SCOPE_AGENT);
                    if (v < (unsigned)(t + 1)) __builtin_amdgcn_s_sleep(2);
                } while (v < (unsigned)(t + 1));
            }
            __syncthreads();
            {   // stage xi cols 0..1023 -> s_xi[2048..3072)
                const float* xs = xib + bg * 3072;
                f32x4 d0;
                cld1(d0, xs + tid * 4);
                *(f32x4*)&s_xi[2048 + tid * 4] = d0;
            }
            __syncthreads();
            const float* xL = s_xi + 2048;            // xL[i] = xi[i]

            float accR[12];
#pragma unroll
            for (int i = 0; i < 12; i++) accR[i] = 0.f;
            for (int w = tid; w < 512; w += 256) {
                float rk0 = xL[w], rk1 = xL[512 + w];
                accR[10] += rk0 * rk0; accR[11] += rk1 * rk1;
#pragma unroll
                for (int n = 0; n < 5; n++) {
                    float mn_ = s_M[n][w];
                    accR[n]     += rk0 * mn_;
                    accR[5 + n] += rk1 * mn_;
                }
            }
            blk_reduce<12>(accR, s_red, s_dotR, tid);
            if (tid < 10) {
                int rr = tid / 5, ii = tid % 5;
                float sim = s_dotR[rr * 5 + ii] /
                            ((sqrtf(s_dotR[10 + rr]) + EPSC) * (sqrtf(s_dotB[ii]) + EPSC));
                s_z[rr][ii] = s_rb[rr] * sim;
            }
            __syncthreads();
            if (tid < 10) {
                int rr = tid / 5, ii = tid % 5;
                float mx = s_z[rr][0];
#pragma unroll
                for (int m2 = 1; m2 < 5; m2++) mx = fmaxf(mx, s_z[rr][m2]);
                float sum = 0.f;
#pragma unroll
                for (int m2 = 0; m2 < 5; m2++) sum += expf(s_z[rr][m2] - mx);
                float cr = expf(s_z[rr][ii] - mx) / sum;
                float wn = s_pi[rr][0] * s_bw[rr][ii] + s_pi[rr][1] * cr + s_pi[rr][2] * s_fw[rr][ii];
                s_wrnew[rr][ii] = wn; st_wr[rr * 5 + ii] = wn;
            }
            __syncthreads();
            for (int idx = tid; idx < 1024; idx += 256) {
                int rr = idx >> 9, w = idx & 511;
                float rv = 0.f;
#pragma unroll
                for (int n = 0; n < 5; n++) rv += s_wrnew[rr][n] * s_M[n][w];
                gst(&rbuf[bg * 1024 + idx], rv);        // coherent
                hr[((size_t)t * 16 + bg) * 1536 + 512 + idx] = rv;
            }
            __builtin_amdgcn_s_waitcnt(0);
            __syncthreads();
            if (tid == 0)
                __hip_atomic_store(&rf[bg * 32], (unsigned)(t + 1),
                                   __ATOMIC_RELAXED, __HIP_MEMORY_SCOPE_AGENT);
        }
        // non-M blocks: straight to next step (h-stage hides under rf-wait)
    }
}

// ---------------------------------------------------------------------------
// Prologue: gates_x[tok][col] = b_lstm[col] + sum_{k<512} emb[src_tok,k]*W_ih[col,k]
// ---------------------------------------------------------------------------
__global__ __launch_bounds__(256) void k_embgx(
    const int* __restrict__ src, const float* __restrict__ emb,
    const float* __restrict__ W_ih, const float* __restrict__ b_lstm,
    float* __restrict__ gx)
{
    __shared__ __align__(16) float As[16][68];
    __shared__ __align__(16) float Bs[16][68];
    const int tid = threadIdx.x;
    const int bm = blockIdx.x, bn = blockIdx.y;
    const int tm = tid >> 4, tn = tid & 15;
    float acc[4][4] = {};
    for (int k0 = 0; k0 < 512; k0 += 16) {
#pragma unroll
        for (int i = 0; i < 4; i++) {
            int idx = tid + 256 * i;
            int m = idx >> 4, kk = idx & 15;
            int tok = bm * 64 + m;
            int row = src[(tok & 15) * 128 + (tok >> 4)];
            As[kk][m] = emb[(size_t)row * 512 + k0 + kk];
        }
#pragma unroll
        for (int i = 0; i < 4; i++) {
            int idx = tid + 256 * i;
            int n = idx >> 4, kk = idx & 15;
            Bs[kk][n] = W_ih[(size_t)(bn * 64 + n) * 1536 + k0 + kk];
        }
        __syncthreads();
#pragma unroll
        for (int kk = 0; kk < 16; kk++) {
            float4 av = *(const float4*)&As[kk][tm * 4];
            float4 bv = *(const float4*)&Bs[kk][tn * 4];
            float a[4] = {av.x, av.y, av.z, av.w};
            float b[4] = {bv.x, bv.y, bv.z, bv.w};
#pragma unroll
            for (int i = 0; i < 4; i++)
#pragma unroll
                for (int j = 0; j < 4; j++) acc[i][j] = fmaf(a[i], b[j], acc[i][j]);
        }
        __syncthreads();
    }
#pragma unroll
    for (int i = 0; i < 4; i++) {
        int tok = bm * 64 + tm * 4 + i;
#pragma unroll
        for (int j = 0; j < 4; j++) {
            int col = bn * 64 + tn * 4 + j;
            gx[(size_t)tok * 2048 + col] = acc[i][j] + b_lstm[col];
        }
    }
}

// ---------------------------------------------------------------------------
// Epilogue: out[b,s,q] = b_out[q] + sum_k hr[s,b,k]*W_out[k,q]
// ---------------------------------------------------------------------------
__global__ __launch_bounds__(256) void k_out(
    const float* __restrict__ hr, const float* __restrict__ W_out,
    const float* __restrict__ b_out, float* __restrict__ out)
{
    __shared__ __align__(16) float As[16][68];
    __shared__ __align__(16) float Bs[16][68];
    const int tid = threadIdx.x;
    const int bm = blockIdx.x, bn = blockIdx.y;
    const int tm = tid >> 4, tn = tid & 15;
    float acc[4][4] = {};
    for (int k0 = 0; k0 < 1536; k0 += 16) {
#pragma unroll
        for (int i = 0; i < 4; i++) {
            int idx = tid + 256 * i;
            int m = idx >> 4, kk = idx & 15;
            As[kk][m] = hr[(size_t)(bm * 64 + m) * 1536 + k0 + kk];
        }
#pragma unroll
        for (int i = 0; i < 4; i++) {
            int idx = tid + 256 * i;
            int kk = idx >> 6, n = idx & 63;
            Bs[kk][n] = W_out[(size_t)(k0 + kk) * 512 + bn * 64 + n];
        }
        __syncthreads();
#pragma unroll
        for (int kk = 0; kk < 16; kk++) {
            float4 av = *(const float4*)&As[kk][tm * 4];
            float4 bv = *(const float4*)&Bs[kk][tn * 4];
            float a[4] = {av.x, av.y, av.z, av.w};
            float b[4] = {bv.x, bv.y, bv.z, bv.w};
#pragma unroll
            for (int i = 0; i < 4; i++)
#pragma unroll
                for (int j = 0; j < 4; j++) acc[i][j] = fmaf(a[i], b[j], acc[i][j]);
        }
        __syncthreads();
    }
#pragma unroll
    for (int i = 0; i < 4; i++) {
        int tok = bm * 64 + tm * 4 + i;
        int b_ = tok & 15, s_ = tok >> 4;
#pragma unroll
        for (int j = 0; j < 4; j++) {
            int qn = bn * 64 + tn * 4 + j;
            out[(size_t)((b_ << 7) + s_) * 512 + qn] = acc[i][j] + b_out[qn];
        }
    }
}

extern "C" void kernel_launch(void* const* d_in, const int* in_sizes, int n_in,
                              void* d_out, int out_size, void* d_ws, size_t ws_size,
                              hipStream_t stream)
{
    const int*   src    = (const int*)d_in[0];
    const float* emb    = (const float*)d_in[2];
    const float* W_ih   = (const float*)d_in[3];
    const float* W_hh   = (const float*)d_in[4];
    const float* b_lstm = (const float*)d_in[5];
    const float* W_int  = (const float*)d_in[6];
    const float* b_int  = (const float*)d_in[7];
    const float* W_out  = (const float*)d_in[8];
    const float* b_out  = (const float*)d_in[9];

    float* ws  = (float*)d_ws;
    float* out = (float*)d_out;

    float*    hbuf  = ws + OFF_H;
    float*    rbuf  = ws + OFF_R;
    unsigned* flags = (unsigned*)(ws + OFF_FLAGS);
    unsigned* go    = (unsigned*)(ws + OFF_GO);
    unsigned* xf    = (unsigned*)(ws + OFF_XF);
    unsigned* xfa   = (unsigned*)(ws + OFF_XFA);
    unsigned* rf    = (unsigned*)(ws + OFF_RF);
    float*    xib   = ws + OFF_XI;
    float*    gx    = ws + OFF_GX;
    float*    hrb   = ws + OFF_HR;

    // zero recurrent state + all sync flags (deterministic across replays)
    hipMemsetAsync(ws, 0, STATE_END * sizeof(float), stream);

    // prologue: token-parallel x-part of gates (+ bias)
    k_embgx<<<dim3(32, 32), 256, 0, stream>>>(src, emb, W_ih, b_lstm, gx);

    // main loop: 2 independent 64-block groups (batches 0-7 / 8-15)
    k_main<<<dim3(NBLK), dim3(256), 0, stream>>>(
        W_ih, W_hh, W_int, b_int, gx, hbuf, rbuf, xib, hrb, out,
        flags, go, xf, xfa, rf);

    // epilogue: token-parallel output projection
    k_out<<<dim3(32, 8), 256, 0, stream>>>(hrb, W_out, b_out, out);
}

// Round 14
// 3664.689 us; speedup vs baseline: 1.3318x; 1.1306x over previous
//
#include <hip/hip_runtime.h>
#include <math.h>

// B=16, S=128, H=512, V=50000, N=5, R=2, Wd=512, XI=2573
#define EPSC 1e-6f
#define NBLK 256
#define GBLK 64     // blocks per group; 4 independent groups of 4 batches

// ws layout (float offsets)
#define OFF_H     0u         // hbuf[2][16][512]
#define OFF_R     16384u     // r[16][1024]
#define OFF_FLAGS 32768u     // bar1 arrival flags: 256 x 32 u32
#define OFF_GO    40960u     // bar1 go lines:      256 x 32 u32
#define OFF_XF    49152u     // xi-producer flags:  256 x 32 u32
#define OFF_RF    57344u     // r-producer flags:   16 x 32 u32 (+pad)
#define STATE_END 58368u
#define OFF_XI    58368u     // xi[16][3072] (padded rows)
#define OFF_GX    107520u    // gates_x[128][16][2048]
#define OFF_HR    4301824u   // hr[128][16][1536]
// end 7447552 floats = 29.79 MB

typedef float f32x4 __attribute__((ext_vector_type(4)));

__device__ __forceinline__ float sigmf(float x) { return 1.0f / (1.0f + expf(-x)); }
__device__ __forceinline__ float oneplusf(float x) {
    return 1.0f + fmaxf(x, 0.0f) + log1pf(expf(-fabsf(x)));
}

// coherent scalar store (agent scope, bypasses L1/L2) — proven r3-r13
__device__ __forceinline__ void gst(float* p, float v) {
    __hip_atomic_store((unsigned*)p, __float_as_uint(v),
                       __ATOMIC_RELAXED, __HIP_MEMORY_SCOPE_AGENT);
}

// 6 coherent dwordx4 loads: h (2, stride 1024B) + r (4, stride 1024B), 1 waitcnt
__device__ __forceinline__ void ld6g(
    f32x4& h0, f32x4& h1,
    f32x4& r0, f32x4& r1, f32x4& r2, f32x4& r3,
    const float* ph, const float* pr)
{
    asm volatile(
        "global_load_dwordx4 %0, %6, off sc0 sc1\n\t"
        "global_load_dwordx4 %1, %6, off offset:1024 sc0 sc1\n\t"
        "global_load_dwordx4 %2, %7, off sc0 sc1\n\t"
        "global_load_dwordx4 %3, %7, off offset:1024 sc0 sc1\n\t"
        "global_load_dwordx4 %4, %7, off offset:2048 sc0 sc1\n\t"
        "global_load_dwordx4 %5, %7, off offset:3072 sc0 sc1\n\t"
        "s_waitcnt vmcnt(0)"
        : "=&v"(h0), "=&v"(h1), "=&v"(r0), "=&v"(r1), "=&v"(r2), "=&v"(r3)
        : "v"(ph), "v"(pr)
        : "memory");
}

// 2 coherent dwordx4 loads, one base, offsets 0/1024 B.
__device__ __forceinline__ void ld2h(f32x4& d0, f32x4& d1, const float* p)
{
    asm volatile(
        "global_load_dwordx4 %0, %2, off sc0 sc1\n\t"
        "global_load_dwordx4 %1, %2, off offset:1024 sc0 sc1\n\t"
        "s_waitcnt vmcnt(0)"
        : "=&v"(d0), "=&v"(d1)
        : "v"(p)
        : "memory");
}

__device__ __forceinline__ void cld3(
    f32x4& d0, f32x4& d1, f32x4& d2,
    const float* p0, const float* p1, const float* p2)
{
    asm volatile(
        "global_load_dwordx4 %0, %3, off sc0 sc1\n\t"
        "global_load_dwordx4 %1, %4, off sc0 sc1\n\t"
        "global_load_dwordx4 %2, %5, off sc0 sc1\n\t"
        "s_waitcnt vmcnt(0)"
        : "=&v"(d0), "=&v"(d1), "=&v"(d2)
        : "v"(p0), "v"(p1), "v"(p2)
        : "memory");
}

// Fence-free 2-hop mailbox barrier, PER GROUP (1 poller per line).
__device__ __forceinline__ void gsync(unsigned* flags, unsigned* go, unsigned gen,
                                      int bi, int bl, int g, int tid)
{
    __builtin_amdgcn_s_waitcnt(0);   // drain this wave's payload stores
    __syncthreads();
    if (tid == 0)
        __hip_atomic_store(&flags[bi * 32], gen, __ATOMIC_RELAXED, __HIP_MEMORY_SCOPE_AGENT);
    if (bl == 0) {
        if (tid < GBLK) {
            unsigned v;
            do {
                v = __hip_atomic_load(&flags[(g * GBLK + tid) * 32], __ATOMIC_RELAXED,
                                      __HIP_MEMORY_SCOPE_AGENT);
                if (v < gen) __builtin_amdgcn_s_sleep(1);
            } while (v < gen);
        }
        __syncthreads();
        if (tid < GBLK)
            __hip_atomic_store(&go[(g * GBLK + tid) * 32], gen, __ATOMIC_RELAXED,
                               __HIP_MEMORY_SCOPE_AGENT);
    }
    if (tid == 0) {
        unsigned v;
        do {
            v = __hip_atomic_load(&go[bi * 32], __ATOMIC_RELAXED, __HIP_MEMORY_SCOPE_AGENT);
            if (v < gen) __builtin_amdgcn_s_sleep(1);
        } while (v < gen);
    }
    __syncthreads();
}

template <int K>
__device__ __forceinline__ void blk_reduce(float* v, float (*s_red)[20],
                                           float* outp, int tid)
{
#pragma unroll
    for (int i = 0; i < K; i++) {
        float x = v[i];
        for (int o = 32; o > 0; o >>= 1) x += __shfl_down(x, o, 64);
        if ((tid & 63) == 0) s_red[tid >> 6][i] = x;
    }
    __syncthreads();
    if (tid < K) outp[tid] = s_red[0][tid] + s_red[1][tid] + s_red[2][tid] + s_red[3][tid];
    __syncthreads();
}

// ---------------------------------------------------------------------------
// Persistent kernel: 4 independent groups x 64 blocks x 256 threads.
// Group g handles batches g*4 .. g*4+3; groups never synchronize.
// ---------------------------------------------------------------------------
__global__ __launch_bounds__(256, 1) void k_main(
    const float* __restrict__ W_ih, const float* __restrict__ W_hh,
    const float* __restrict__ W_int, const float* __restrict__ b_int,
    const float* __restrict__ gx, float* __restrict__ hbuf,
    float* __restrict__ rbuf, float* __restrict__ xib,
    float* __restrict__ hr, float* __restrict__ out,
    unsigned* __restrict__ flags, unsigned* __restrict__ go,
    unsigned* __restrict__ xf, unsigned* __restrict__ rf)
{
    const int tid = threadIdx.x;
    const int bi  = blockIdx.x;
    const int g   = bi >> 6;         // group 0..3
    const int bl  = bi & 63;         // block-in-group
    const int bg0 = g * 4;           // first global batch of group

    // ---- LDS (~53 KB) ----
    __shared__ __align__(16) float big_u[6656];   // G: 4x1664 / X: 4x592
    __shared__ __align__(16) float s_xi[3072];    // M: staged xi
    __shared__ float s_part[512];
    __shared__ float s_tot[128];
    __shared__ float c_s[32];                     // persistent c (8 j x 4 b)
    __shared__ __align__(16) float s_M[5][520];   // persistent M (M-blocks)
    __shared__ float st_u[5], st_p[5], st_L[25], st_wr[10], st_ww[5];
    __shared__ float s_red[4][20];
    __shared__ float s_rb[2], s_wb, s_fg[2], s_ga, s_gw, s_pi[2][3];
    __shared__ float s_wrold[2][5], s_uu[5], s_a[5], s_wwn[5];
    __shared__ float s_pold[5], s_Lnew[25];
    __shared__ float s_zw[5], s_z[2][5], s_fw[2][5], s_bw[2][5];
    __shared__ float s_dotA[11], s_dotB[17], s_wrnew[2][5];

    // ---- init persistent LDS state ----
    if (tid < 32) c_s[tid] = 0.f;
    if (bl < 4) {
        for (int i = tid; i < 5 * 520; i += 256) (&s_M[0][0])[i] = 0.f;
        if (tid < 5)  { st_u[tid] = 0.f; st_p[tid] = 0.f; st_ww[tid] = 0.f; }
        if (tid < 25) st_L[tid] = 0.f;
        if (tid < 10) st_wr[tid] = 0.f;
    }
    __syncthreads();

    // thread roles
    const int cq = tid & 7;            // j-offset within block
    const int ks = tid >> 3;           // 0..31 k-chunk of 48
    const int jcol = bl * 8 + cq;      // hidden index 0..511
    const int b4 = tid >> 6, sg = tid & 63;   // staging roles

#pragma unroll 1
    for (int t = 0; t < 128; t++) {
        const float* h_in  = hbuf + (t & 1) * 8192;
        float*       h_out = hbuf + ((t + 1) & 1) * 8192;

        // gx prefetch (cached, L2-hot)
        float gxv = 0.f;
        if (tid < 128) {
            int c = tid & 31, b = tid >> 5;
            int col = (c >> 3) * 512 + bl * 8 + (c & 7);
            gxv = gx[((size_t)t * 16 + bg0 + b) * 2048 + col];
        }
        // ---- wait for r(t) ----
        if (tid < 4) {
            unsigned v;
            do {
                v = __hip_atomic_load(&rf[(bg0 + tid) * 32], __ATOMIC_RELAXED,
                                      __HIP_MEMORY_SCOPE_AGENT);
                if (v < (unsigned)t) __builtin_amdgcn_s_sleep(4);
            } while (v < (unsigned)t);
        }
        __syncthreads();

        // ================= phase G: stage xin + gate MACs =================
        {
            const float* ph = h_in + (bg0 + b4) * 512 + sg * 4;
            const float* pr = rbuf + (bg0 + b4) * 1024 + sg * 4;
            f32x4 h0, h1, r0, r1, r2, r3;
            ld6g(h0, h1, r0, r1, r2, r3, ph, pr);
#define STG(kk, D) { int k = (kk); int cc = k / 48; \
                     *(f32x4*)&big_u[b4 * 1664 + cc * 52 + (k - cc * 48)] = D; }
            STG(sg * 4 + 0 * 256, h0)        STG(sg * 4 + 1 * 256, h1)
            STG(512 + sg * 4 + 0 * 256, r0)  STG(512 + sg * 4 + 1 * 256, r1)
            STG(512 + sg * 4 + 2 * 256, r2)  STG(512 + sg * 4 + 3 * 256, r3)
#undef STG
        }
        __syncthreads();

        float acc[4][4];
#pragma unroll
        for (int g_ = 0; g_ < 4; g_++)
#pragma unroll
            for (int b = 0; b < 4; b++) acc[g_][b] = 0.f;
#pragma unroll
        for (int i = 0; i < 12; i++) {
            int kg = ks * 48 + i * 4;
            f32x4 w[4];
#pragma unroll
            for (int g_ = 0; g_ < 4; g_++) {
                const float* wp = (kg < 512)
                    ? W_hh + (size_t)(g_ * 512 + jcol) * 512 + kg
                    : W_ih + (size_t)(g_ * 512 + jcol) * 1536 + kg;
                w[g_] = *(const f32x4*)wp;
            }
#pragma unroll
            for (int b = 0; b < 4; b++) {
                f32x4 xv = *(const f32x4*)&big_u[b * 1664 + ks * 52 + i * 4];
#pragma unroll
                for (int g_ = 0; g_ < 4; g_++) {
                    acc[g_][b] = fmaf(w[g_][0], xv[0], acc[g_][b]);
                    acc[g_][b] = fmaf(w[g_][1], xv[1], acc[g_][b]);
                    acc[g_][b] = fmaf(w[g_][2], xv[2], acc[g_][b]);
                    acc[g_][b] = fmaf(w[g_][3], xv[3], acc[g_][b]);
                }
            }
        }
#pragma unroll
        for (int g_ = 0; g_ < 4; g_++)
#pragma unroll
            for (int b = 0; b < 4; b++) {
                float x = acc[g_][b];
                x += __shfl_xor(x, 8, 64);
                x += __shfl_xor(x, 16, 64);
                x += __shfl_xor(x, 32, 64);
                acc[g_][b] = x;
            }
        {
            int wv = tid >> 6;
            if ((tid & 63) < 8) {
#pragma unroll
                for (int g_ = 0; g_ < 4; g_++)
#pragma unroll
                    for (int b = 0; b < 4; b++)
                        s_part[((wv * 4 + g_) * 8 + cq) * 4 + b] = acc[g_][b];
            }
        }
        __syncthreads();
        if (tid < 128) {
            int c = tid & 31, b = tid >> 5;
            int g_ = c >> 3, jq = c & 7;
            float tot = gxv;
#pragma unroll
            for (int w = 0; w < 4; w++)
                tot += s_part[((w * 4 + g_) * 8 + jq) * 4 + b];
            s_tot[c * 4 + b] = tot;
        }
        __syncthreads();
        if (tid < 32) {
            int jl = tid & 7, b = tid >> 3;
            float gi  = s_tot[(0 * 8 + jl) * 4 + b];
            float gf  = s_tot[(1 * 8 + jl) * 4 + b];
            float gg  = s_tot[(2 * 8 + jl) * 4 + b];
            float go_ = s_tot[(3 * 8 + jl) * 4 + b];
            float cc = sigmf(gf) * c_s[jl * 4 + b] + sigmf(gi) * tanhf(gg);
            float hh = sigmf(go_) * tanhf(cc);
            c_s[jl * 4 + b] = cc;
            int j = bl * 8 + jl;
            int bgl = bg0 + b;
            gst(h_out + bgl * 512 + j, hh);               // coherent
            hr[((size_t)t * 16 + bgl) * 1536 + j] = hh;   // cached sink
            if (t == 127) {
                out[1048576 + bgl * 512 + j] = hh;
                out[1048576 + 8192 + bgl * 512 + j] = cc;
            }
        }
        gsync(flags, go, (unsigned)(t + 1), bi, bl, g, tid);   // h published

        // ================= phase X: xi = h @ W_int + b_int =================
        {
            // stage h_out (4 x 512), chunk-36 rows
            {
                const float* ph = h_out + (bg0 + b4) * 512 + sg * 4;
                f32x4 e0, e1;
                ld2h(e0, e1, ph);
#define STX(j, E) { int k = sg * 4 + (j) * 256; \
                    *(f32x4*)&big_u[b4 * 592 + (k >> 5) * 36 + (k & 31)] = E; }
                STX(0, e0) STX(1, e1)
#undef STX
            }
            __syncthreads();
            const int ql  = tid & 15;
            const int kcl = tid >> 4;      // 0..15, 32 k each
#pragma unroll 1
            for (int p = 0; p < 3; p++) {
                if (p == 2 && bl >= 33) break;
                int q0 = p * 1024 + bl * 16;          // contiguous 16-col stripe
                int q  = q0 + ql;
                int qc = (q < 2573) ? q : 2572;
                float wxr[32];
#pragma unroll
                for (int i = 0; i < 32; i++)
                    wxr[i] = W_int[(size_t)(kcl * 32 + i) * 2573 + qc];
                float ax[4];
#pragma unroll
                for (int b = 0; b < 4; b++) ax[b] = 0.f;
#pragma unroll
                for (int b = 0; b < 4; b++) {
                    const f32x4* hp = (const f32x4*)&big_u[b * 592 + kcl * 36];
#pragma unroll
                    for (int i4 = 0; i4 < 8; i4++) {
                        f32x4 hv = hp[i4];
                        ax[b] = fmaf(wxr[i4 * 4 + 0], hv[0], ax[b]);
                        ax[b] = fmaf(wxr[i4 * 4 + 1], hv[1], ax[b]);
                        ax[b] = fmaf(wxr[i4 * 4 + 2], hv[2], ax[b]);
                        ax[b] = fmaf(wxr[i4 * 4 + 3], hv[3], ax[b]);
                    }
                }
#pragma unroll
                for (int b = 0; b < 4; b++) {
                    float x = ax[b];
                    x += __shfl_xor(x, 16, 64);
                    x += __shfl_xor(x, 32, 64);
                    ax[b] = x;
                }
                {
                    int wv = tid >> 6;
                    if ((tid & 63) < 16) {
#pragma unroll
                        for (int b = 0; b < 4; b++)
                            s_part[(wv * 16 + ql) * 4 + b] = ax[b];
                    }
                }
                __syncthreads();
                if (tid < 64) {
                    int q_l = tid >> 2, b = tid & 3;
                    int qq = q0 + q_l;
                    if (qq < 2573) {
                        float v = b_int[qq];
#pragma unroll
                        for (int w = 0; w < 4; w++)
                            v += s_part[(w * 16 + q_l) * 4 + b];
                        gst(&xib[(bg0 + b) * 3072 + qq], v);    // coherent
                    }
                }
                __syncthreads();
            }
        }
        // announce xi completion
        __builtin_amdgcn_s_waitcnt(0);
        __syncthreads();
        if (tid == 0)
            __hip_atomic_store(&xf[bi * 32], (unsigned)(t + 1),
                               __ATOMIC_RELAXED, __HIP_MEMORY_SCOPE_AGENT);

        // ================= phase M: memory machinery (bl 0..3) =================
        if (bl < 4) {
            const int bg = bg0 + bl;
            if (tid < GBLK) {
                unsigned v;
                do {
                    v = __hip_atomic_load(&xf[(g * GBLK + tid) * 32], __ATOMIC_RELAXED,
                                          __HIP_MEMORY_SCOPE_AGENT);
                    if (v < (unsigned)(t + 1)) __builtin_amdgcn_s_sleep(2);
                } while (v < (unsigned)(t + 1));
            }
            __syncthreads();
            {
                const float* xs = xib + bg * 3072;
                f32x4 d0, d1, d2;
                cld3(d0, d1, d2,
                     xs + (tid + 0) * 4, xs + (tid + 256) * 4, xs + (tid + 512) * 4);
                *(f32x4*)&s_xi[(tid + 0) * 4]   = d0;
                *(f32x4*)&s_xi[(tid + 256) * 4] = d1;
                *(f32x4*)&s_xi[(tid + 512) * 4] = d2;
            }
            __syncthreads();
            const float* xb = s_xi;

            if (tid == 0) {
                s_wb = oneplusf(xb[1538]);
                s_ga = sigmf(xb[2565]);
                s_gw = sigmf(xb[2566]);
            }
            if (tid == 1 || tid == 2) {
                int rr = tid - 1;
                s_rb[rr] = oneplusf(xb[1024 + rr]);
                s_fg[rr] = sigmf(xb[2563 + rr]);
                float z0 = xb[2567 + rr * 3], z1 = xb[2568 + rr * 3], z2 = xb[2569 + rr * 3];
                float mx = fmaxf(z0, fmaxf(z1, z2));
                float e0 = expf(z0 - mx), e1 = expf(z1 - mx), e2 = expf(z2 - mx);
                float s = e0 + e1 + e2;
                s_pi[rr][0] = e0 / s; s_pi[rr][1] = e1 / s; s_pi[rr][2] = e2 / s;
            }
            if (tid >= 32 && tid < 42) { int i = tid - 32; s_wrold[i / 5][i % 5] = st_wr[i]; }
            if (tid >= 64 && tid < 69) { s_pold[tid - 64] = st_p[tid - 64]; }
            __syncthreads();
            if (tid < 5) {
                float psi = (1.f - s_fg[0] * s_wrold[0][tid]) * (1.f - s_fg[1] * s_wrold[1][tid]);
                float un = (st_u[tid] + st_ww[tid] - st_u[tid] * st_ww[tid]) * psi;
                s_uu[tid] = un; st_u[tid] = un;
            }
            __syncthreads();
            if (tid < 5) {
                float excl = 1.f;
#pragma unroll
                for (int m2 = 0; m2 < 5; m2++) {
                    bool before = (s_uu[m2] < s_uu[tid]) || (s_uu[m2] == s_uu[tid] && m2 < tid);
                    if (before) excl *= s_uu[m2];
                }
                s_a[tid] = (1.f - s_uu[tid]) * excl;
            }
            float accA[11];
#pragma unroll
            for (int i = 0; i < 11; i++) accA[i] = 0.f;
            for (int w = tid; w < 512; w += 256) {
                float wk = xb[1026 + w];
                accA[10] += wk * wk;
#pragma unroll
                for (int n = 0; n < 5; n++) {
                    float m_ = s_M[n][w];
                    accA[n]     += m_ * m_;
                    accA[5 + n] += wk * m_;
                }
            }
            blk_reduce<11>(accA, s_red, s_dotA, tid);
            if (tid < 5) {
                float sim = s_dotA[5 + tid] /
                            ((sqrtf(s_dotA[10]) + EPSC) * (sqrtf(s_dotA[tid]) + EPSC));
                s_zw[tid] = s_wb * sim;
            }
            __syncthreads();
            if (tid < 5) {
                float mx = s_zw[0];
#pragma unroll
                for (int m2 = 1; m2 < 5; m2++) mx = fmaxf(mx, s_zw[m2]);
                float sum = 0.f;
#pragma unroll
                for (int m2 = 0; m2 < 5; m2++) sum += expf(s_zw[m2] - mx);
                float cw = expf(s_zw[tid] - mx) / sum;
                float w_ = s_gw * (s_ga * s_a[tid] + (1.f - s_ga) * cw);
                s_wwn[tid] = w_; st_ww[tid] = w_;
            }
            __syncthreads();
            float accB[17];
#pragma unroll
            for (int i = 0; i < 17; i++) accB[i] = 0.f;
            for (int w = tid; w < 512; w += 256) {
                float ew = sigmf(xb[1539 + w]);
                float vw = xb[2051 + w];
                float rk0 = xb[w], rk1 = xb[512 + w];
                accB[15] += rk0 * rk0; accB[16] += rk1 * rk1;
#pragma unroll
                for (int n = 0; n < 5; n++) {
                    float m_ = s_M[n][w];
                    float mn_ = m_ * (1.f - s_wwn[n] * ew) + s_wwn[n] * vw;
                    s_M[n][w] = mn_;
                    accB[n]      += mn_ * mn_;
                    accB[5 + n]  += rk0 * mn_;
                    accB[10 + n] += rk1 * mn_;
                }
            }
            blk_reduce<17>(accB, s_red, s_dotB, tid);
            if (tid < 25) {
                int i2 = tid / 5, j2 = tid % 5;
                float Ln = (i2 == j2) ? 0.f
                         : (1.f - s_wwn[i2] - s_wwn[j2]) * st_L[tid] + s_wwn[i2] * s_pold[j2];
                s_Lnew[tid] = Ln; st_L[tid] = Ln;
            }
            __syncthreads();
            if (tid < 5) {
                float wsum = s_wwn[0] + s_wwn[1] + s_wwn[2] + s_wwn[3] + s_wwn[4];
                st_p[tid] = (1.f - wsum) * s_pold[tid] + s_wwn[tid];
            }
            if (tid < 10) {
                int rr = tid / 5, ii = tid % 5;
                float fw = 0.f, bw = 0.f;
#pragma unroll
                for (int j2 = 0; j2 < 5; j2++) {
                    fw += s_Lnew[ii * 5 + j2] * s_wrold[rr][j2];
                    bw += s_Lnew[j2 * 5 + ii] * s_wrold[rr][j2];
                }
                s_fw[rr][ii] = fw; s_bw[rr][ii] = bw;
                float sim = s_dotB[5 + rr * 5 + ii] /
                            ((sqrtf(s_dotB[15 + rr]) + EPSC) * (sqrtf(s_dotB[ii]) + EPSC));
                s_z[rr][ii] = s_rb[rr] * sim;
            }
            __syncthreads();
            if (tid < 10) {
                int rr = tid / 5, ii = tid % 5;
                float mx = s_z[rr][0];
#pragma unroll
                for (int m2 = 1; m2 < 5; m2++) mx = fmaxf(mx, s_z[rr][m2]);
                float sum = 0.f;
#pragma unroll
                for (int m2 = 0; m2 < 5; m2++) sum += expf(s_z[rr][m2] - mx);
                float cr = expf(s_z[rr][ii] - mx) / sum;
                float wn = s_pi[rr][0] * s_bw[rr][ii] + s_pi[rr][1] * cr + s_pi[rr][2] * s_fw[rr][ii];
                s_wrnew[rr][ii] = wn; st_wr[rr * 5 + ii] = wn;
            }
            __syncthreads();
            for (int idx = tid; idx < 1024; idx += 256) {
                int rr = idx >> 9, w = idx & 511;
                float rv = 0.f;
#pragma unroll
                for (int n = 0; n < 5; n++) rv += s_wrnew[rr][n] * s_M[n][w];
                gst(&rbuf[bg * 1024 + idx], rv);        // coherent
                hr[((size_t)t * 16 + bg) * 1536 + 512 + idx] = rv;
            }
            __builtin_amdgcn_s_waitcnt(0);
            __syncthreads();
            if (tid == 0)
                __hip_atomic_store(&rf[bg * 32], (unsigned)(t + 1),
                                   __ATOMIC_RELAXED, __HIP_MEMORY_SCOPE_AGENT);
        }
        // non-M blocks: straight to next rf-wait
    }
}

// ---------------------------------------------------------------------------
// Prologue: gates_x[tok][col] = b_lstm[col] + sum_{k<512} emb[src_tok,k]*W_ih[col,k]
// ---------------------------------------------------------------------------
__global__ __launch_bounds__(256) void k_embgx(
    const int* __restrict__ src, const float* __restrict__ emb,
    const float* __restrict__ W_ih, const float* __restrict__ b_lstm,
    float* __restrict__ gx)
{
    __shared__ __align__(16) float As[16][68];
    __shared__ __align__(16) float Bs[16][68];
    const int tid = threadIdx.x;
    const int bm = blockIdx.x, bn = blockIdx.y;
    const int tm = tid >> 4, tn = tid & 15;
    float acc[4][4] = {};
    for (int k0 = 0; k0 < 512; k0 += 16) {
#pragma unroll
        for (int i = 0; i < 4; i++) {
            int idx = tid + 256 * i;
            int m = idx >> 4, kk = idx & 15;
            int tok = bm * 64 + m;
            int row = src[(tok & 15) * 128 + (tok >> 4)];
            As[kk][m] = emb[(size_t)row * 512 + k0 + kk];
        }
#pragma unroll
        for (int i = 0; i < 4; i++) {
            int idx = tid + 256 * i;
            int n = idx >> 4, kk = idx & 15;
            Bs[kk][n] = W_ih[(size_t)(bn * 64 + n) * 1536 + k0 + kk];
        }
        __syncthreads();
#pragma unroll
        for (int kk = 0; kk < 16; kk++) {
            float4 av = *(const float4*)&As[kk][tm * 4];
            float4 bv = *(const float4*)&Bs[kk][tn * 4];
            float a[4] = {av.x, av.y, av.z, av.w};
            float b[4] = {bv.x, bv.y, bv.z, bv.w};
#pragma unroll
            for (int i = 0; i < 4; i++)
#pragma unroll
                for (int j = 0; j < 4; j++) acc[i][j] = fmaf(a[i], b[j], acc[i][j]);
        }
        __syncthreads();
    }
#pragma unroll
    for (int i = 0; i < 4; i++) {
        int tok = bm * 64 + tm * 4 + i;
#pragma unroll
        for (int j = 0; j < 4; j++) {
            int col = bn * 64 + tn * 4 + j;
            gx[(size_t)tok * 2048 + col] = acc[i][j] + b_lstm[col];
        }
    }
}

// ---------------------------------------------------------------------------
// Epilogue: out[b,s,q] = b_out[q] + sum_k hr[s,b,k]*W_out[k,q]
// ---------------------------------------------------------------------------
__global__ __launch_bounds__(256) void k_out(
    const float* __restrict__ hr, const float* __restrict__ W_out,
    const float* __restrict__ b_out, float* __restrict__ out)
{
    __shared__ __align__(16) float As[16][68];
    __shared__ __align__(16) float Bs[16][68];
    const int tid = threadIdx.x;
    const int bm = blockIdx.x, bn = blockIdx.y;
    const int tm = tid >> 4, tn = tid & 15;
    float acc[4][4] = {};
    for (int k0 = 0; k0 < 1536; k0 += 16) {
#pragma unroll
        for (int i = 0; i < 4; i++) {
            int idx = tid + 256 * i;
            int m = idx >> 4, kk = idx & 15;
            As[kk][m] = hr[(size_t)(bm * 64 + m) * 1536 + k0 + kk];
        }
#pragma unroll
        for (int i = 0; i < 4; i++) {
            int idx = tid + 256 * i;
            int kk = idx >> 6, n = idx & 63;
            Bs[kk][n] = W_out[(size_t)(k0 + kk) * 512 + bn * 64 + n];
        }
        __syncthreads();
#pragma unroll
        for (int kk = 0; kk < 16; kk++) {
            float4 av = *(const float4*)&As[kk][tm * 4];
            float4 bv = *(const float4*)&Bs[kk][tn * 4];
            float a[4] = {av.x, av.y, av.z, av.w};
            float b[4] = {bv.x, bv.y, bv.z, bv.w};
#pragma unroll
            for (int i = 0; i < 4; i++)
#pragma unroll
                for (int j = 0; j < 4; j++) acc[i][j] = fmaf(a[i], b[j], acc[i][j]);
        }
        __syncthreads();
    }
#pragma unroll
    for (int i = 0; i < 4; i++) {
        int tok = bm * 64 + tm * 4 + i;
        int b_ = tok & 15, s_ = tok >> 4;
#pragma unroll
        for (int j = 0; j < 4; j++) {
            int qn = bn * 64 + tn * 4 + j;
            out[(size_t)((b_ << 7) + s_) * 512 + qn] = acc[i][j] + b_out[qn];
        }
    }
}

extern "C" void kernel_launch(void* const* d_in, const int* in_sizes, int n_in,
                              void* d_out, int out_size, void* d_ws, size_t ws_size,
                              hipStream_t stream)
{
    const int*   src    = (const int*)d_in[0];
    const float* emb    = (const float*)d_in[2];
    const float* W_ih   = (const float*)d_in[3];
    const float* W_hh   = (const float*)d_in[4];
    const float* b_lstm = (const float*)d_in[5];
    const float* W_int  = (const float*)d_in[6];
    const float* b_int  = (const float*)d_in[7];
    const float* W_out  = (const float*)d_in[8];
    const float* b_out  = (const float*)d_in[9];

    float* ws  = (float*)d_ws;
    float* out = (float*)d_out;

    float*    hbuf  = ws + OFF_H;
    float*    rbuf  = ws + OFF_R;
    unsigned* flags = (unsigned*)(ws + OFF_FLAGS);
    unsigned* go    = (unsigned*)(ws + OFF_GO);
    unsigned* xf    = (unsigned*)(ws + OFF_XF);
    unsigned* rf    = (unsigned*)(ws + OFF_RF);
    float*    xib   = ws + OFF_XI;
    float*    gx    = ws + OFF_GX;
    float*    hrb   = ws + OFF_HR;

    // zero recurrent state + all sync flags (deterministic across replays)
    hipMemsetAsync(ws, 0, STATE_END * sizeof(float), stream);

    // prologue: token-parallel x-part of gates (+ bias)
    k_embgx<<<dim3(32, 32), 256, 0, stream>>>(src, emb, W_ih, b_lstm, gx);

    // main loop: 4 independent 64-block groups (4 batches each), 256 blocks
    k_main<<<dim3(NBLK), dim3(256), 0, stream>>>(
        W_ih, W_hh, W_int, b_int, gx, hbuf, rbuf, xib, hrb, out,
        flags, go, xf, rf);

    // epilogue: token-parallel output projection
    k_out<<<dim3(32, 8), 256, 0, stream>>>(hrb, W_out, b_out, out);
}

// Round 15
// 3584.248 us; speedup vs baseline: 1.3617x; 1.0224x over previous
//
#include <hip/hip_runtime.h>
#include <math.h>

// B=16, S=128, H=512, V=50000, N=5, R=2, Wd=512, XI=2573
#define EPSC 1e-6f
#define NBLK 256
#define GBLK 64     // blocks per group; 4 independent groups of 4 batches

// ws layout (float offsets)
#define OFF_H     0u         // hbuf[2][16][512]
#define OFF_R     16384u     // r[16][1024]
#define OFF_HF    32768u     // h-producer flags:   256 x 32 u32
#define OFF_GO    40960u     // (unused)
#define OFF_XF    49152u     // xi-producer flags:  256 x 32 u32
#define OFF_RF    57344u     // r-producer flags:   16 x 32 u32 (+pad)
#define STATE_END 58368u
#define OFF_XI    58368u     // xi[16][3072] (padded rows)
#define OFF_GX    107520u    // gates_x[128][16][2048]
#define OFF_HR    4301824u   // hr[128][16][1536]
// end 7447552 floats = 29.79 MB

typedef float f32x4 __attribute__((ext_vector_type(4)));

__device__ __forceinline__ float sigmf(float x) { return 1.0f / (1.0f + expf(-x)); }
__device__ __forceinline__ float oneplusf(float x) {
    return 1.0f + fmaxf(x, 0.0f) + log1pf(expf(-fabsf(x)));
}

// coherent scalar store (agent scope, bypasses L1/L2) — proven r3-r14
__device__ __forceinline__ void gst(float* p, float v) {
    __hip_atomic_store((unsigned*)p, __float_as_uint(v),
                       __ATOMIC_RELAXED, __HIP_MEMORY_SCOPE_AGENT);
}

// 6 coherent dwordx4 loads: h (2, stride 1024B) + r (4, stride 1024B), 1 waitcnt
__device__ __forceinline__ void ld6g(
    f32x4& h0, f32x4& h1,
    f32x4& r0, f32x4& r1, f32x4& r2, f32x4& r3,
    const float* ph, const float* pr)
{
    asm volatile(
        "global_load_dwordx4 %0, %6, off sc0 sc1\n\t"
        "global_load_dwordx4 %1, %6, off offset:1024 sc0 sc1\n\t"
        "global_load_dwordx4 %2, %7, off sc0 sc1\n\t"
        "global_load_dwordx4 %3, %7, off offset:1024 sc0 sc1\n\t"
        "global_load_dwordx4 %4, %7, off offset:2048 sc0 sc1\n\t"
        "global_load_dwordx4 %5, %7, off offset:3072 sc0 sc1\n\t"
        "s_waitcnt vmcnt(0)"
        : "=&v"(h0), "=&v"(h1), "=&v"(r0), "=&v"(r1), "=&v"(r2), "=&v"(r3)
        : "v"(ph), "v"(pr)
        : "memory");
}

// 2 coherent dwordx4 loads, one base, offsets 0/1024 B.
__device__ __forceinline__ void ld2h(f32x4& d0, f32x4& d1, const float* p)
{
    asm volatile(
        "global_load_dwordx4 %0, %2, off sc0 sc1\n\t"
        "global_load_dwordx4 %1, %2, off offset:1024 sc0 sc1\n\t"
        "s_waitcnt vmcnt(0)"
        : "=&v"(d0), "=&v"(d1)
        : "v"(p)
        : "memory");
}

__device__ __forceinline__ void cld3(
    f32x4& d0, f32x4& d1, f32x4& d2,
    const float* p0, const float* p1, const float* p2)
{
    asm volatile(
        "global_load_dwordx4 %0, %3, off sc0 sc1\n\t"
        "global_load_dwordx4 %1, %4, off sc0 sc1\n\t"
        "global_load_dwordx4 %2, %5, off sc0 sc1\n\t"
        "s_waitcnt vmcnt(0)"
        : "=&v"(d0), "=&v"(d1), "=&v"(d2)
        : "v"(p0), "v"(p1), "v"(p2)
        : "memory");
}

// post a producer flag (after draining this block's payload stores)
__device__ __forceinline__ void post_flag(unsigned* f, unsigned gen, int bi, int tid)
{
    __builtin_amdgcn_s_waitcnt(0);
    __syncthreads();
    if (tid == 0)
        __hip_atomic_store(&f[bi * 32], gen, __ATOMIC_RELAXED, __HIP_MEMORY_SCOPE_AGENT);
}

// wait for all GBLK producer flags of this group (1 poller per line)
__device__ __forceinline__ void wait_flags(unsigned* f, unsigned gen, int g, int tid)
{
    if (tid < GBLK) {
        unsigned v;
        do {
            v = __hip_atomic_load(&f[(g * GBLK + tid) * 32], __ATOMIC_RELAXED,
                                  __HIP_MEMORY_SCOPE_AGENT);
            if (v < gen) __builtin_amdgcn_s_sleep(1);
        } while (v < gen);
    }
    __syncthreads();
}

template <int K>
__device__ __forceinline__ void blk_reduce(float* v, float (*s_red)[20],
                                           float* outp, int tid)
{
#pragma unroll
    for (int i = 0; i < K; i++) {
        float x = v[i];
        for (int o = 32; o > 0; o >>= 1) x += __shfl_down(x, o, 64);
        if ((tid & 63) == 0) s_red[tid >> 6][i] = x;
    }
    __syncthreads();
    if (tid < K) outp[tid] = s_red[0][tid] + s_red[1][tid] + s_red[2][tid] + s_red[3][tid];
    __syncthreads();
}

// ---------------------------------------------------------------------------
// Persistent kernel: 4 independent groups x 64 blocks x 256 threads.
// Chain per step: rf-wait -> G -> hf(1hop) -> X(2 passes) -> xf -> M -> rf.
// ---------------------------------------------------------------------------
__global__ __launch_bounds__(256, 1) void k_main(
    const float* __restrict__ W_ih, const float* __restrict__ W_hh,
    const float* __restrict__ W_int, const float* __restrict__ b_int,
    const float* __restrict__ gx, float* __restrict__ hbuf,
    float* __restrict__ rbuf, float* __restrict__ xib,
    float* __restrict__ hr, float* __restrict__ out,
    unsigned* __restrict__ hf, unsigned* __restrict__ xf,
    unsigned* __restrict__ rf)
{
    const int tid = threadIdx.x;
    const int bi  = blockIdx.x;
    const int g   = bi >> 6;         // group 0..3
    const int bl  = bi & 63;         // block-in-group
    const int bg0 = g * 4;           // first global batch of group

    // ---- LDS (~53 KB) ----
    __shared__ __align__(16) float big_u[6656];   // G: 4x1664 / X: 4x592
    __shared__ __align__(16) float s_xi[3072];    // M: staged xi
    __shared__ float s_part[512];
    __shared__ float s_tot[128];
    __shared__ float c_s[32];                     // persistent c (8 j x 4 b)
    __shared__ __align__(16) float s_M[5][520];   // persistent M (M-blocks)
    __shared__ float st_u[5], st_p[5], st_L[25], st_wr[10], st_ww[5];
    __shared__ float s_red[4][20];
    __shared__ float s_rb[2], s_wb, s_fg[2], s_ga, s_gw, s_pi[2][3];
    __shared__ float s_wrold[2][5], s_uu[5], s_a[5], s_wwn[5];
    __shared__ float s_pold[5], s_Lnew[25];
    __shared__ float s_zw[5], s_z[2][5], s_fw[2][5], s_bw[2][5];
    __shared__ float s_dotA[11], s_dotB[17], s_wrnew[2][5];

    // ---- init persistent LDS state ----
    if (tid < 32) c_s[tid] = 0.f;
    if (bl < 4) {
        for (int i = tid; i < 5 * 520; i += 256) (&s_M[0][0])[i] = 0.f;
        if (tid < 5)  { st_u[tid] = 0.f; st_p[tid] = 0.f; st_ww[tid] = 0.f; }
        if (tid < 25) st_L[tid] = 0.f;
        if (tid < 10) st_wr[tid] = 0.f;
    }
    __syncthreads();

    // thread roles
    const int cq = tid & 7;            // j-offset within block (G)
    const int ks = tid >> 3;           // 0..31 k-chunk of 48 (G)
    const int jcol = bl * 8 + cq;      // hidden index 0..511
    const int b4 = tid >> 6, sg = tid & 63;   // staging roles
    const int xql  = tid & 31;         // X: col in 32-stripe
    const int xkcl = tid >> 5;         // X: 0..7, 64 k each

#pragma unroll 1
    for (int t = 0; t < 128; t++) {
        const float* h_in  = hbuf + (t & 1) * 8192;
        float*       h_out = hbuf + ((t + 1) & 1) * 8192;

        // gx prefetch (cached, L2-hot)
        float gxv = 0.f;
        if (tid < 128) {
            int c = tid & 31, b = tid >> 5;
            int col = (c >> 3) * 512 + bl * 8 + (c & 7);
            gxv = gx[((size_t)t * 16 + bg0 + b) * 2048 + col];
        }
        // ---- wait for r(t) ----
        if (tid < 4) {
            unsigned v;
            do {
                v = __hip_atomic_load(&rf[(bg0 + tid) * 32], __ATOMIC_RELAXED,
                                      __HIP_MEMORY_SCOPE_AGENT);
                if (v < (unsigned)t) __builtin_amdgcn_s_sleep(1);
            } while (v < (unsigned)t);
        }
        __syncthreads();

        // ================= phase G: stage xin + gate MACs =================
        {
            const float* ph = h_in + (bg0 + b4) * 512 + sg * 4;
            const float* pr = rbuf + (bg0 + b4) * 1024 + sg * 4;
            f32x4 h0, h1, r0, r1, r2, r3;
            ld6g(h0, h1, r0, r1, r2, r3, ph, pr);
#define STG(kk, D) { int k = (kk); int cc = k / 48; \
                     *(f32x4*)&big_u[b4 * 1664 + cc * 52 + (k - cc * 48)] = D; }
            STG(sg * 4 + 0 * 256, h0)        STG(sg * 4 + 1 * 256, h1)
            STG(512 + sg * 4 + 0 * 256, r0)  STG(512 + sg * 4 + 1 * 256, r1)
            STG(512 + sg * 4 + 2 * 256, r2)  STG(512 + sg * 4 + 3 * 256, r3)
#undef STG
        }
        __syncthreads();

        float acc[4][4];
#pragma unroll
        for (int g_ = 0; g_ < 4; g_++)
#pragma unroll
            for (int b = 0; b < 4; b++) acc[g_][b] = 0.f;
#pragma unroll
        for (int i = 0; i < 12; i++) {
            int kg = ks * 48 + i * 4;
            f32x4 w[4];
#pragma unroll
            for (int g_ = 0; g_ < 4; g_++) {
                const float* wp = (kg < 512)
                    ? W_hh + (size_t)(g_ * 512 + jcol) * 512 + kg
                    : W_ih + (size_t)(g_ * 512 + jcol) * 1536 + kg;
                w[g_] = *(const f32x4*)wp;
            }
#pragma unroll
            for (int b = 0; b < 4; b++) {
                f32x4 xv = *(const f32x4*)&big_u[b * 1664 + ks * 52 + i * 4];
#pragma unroll
                for (int g_ = 0; g_ < 4; g_++) {
                    acc[g_][b] = fmaf(w[g_][0], xv[0], acc[g_][b]);
                    acc[g_][b] = fmaf(w[g_][1], xv[1], acc[g_][b]);
                    acc[g_][b] = fmaf(w[g_][2], xv[2], acc[g_][b]);
                    acc[g_][b] = fmaf(w[g_][3], xv[3], acc[g_][b]);
                }
            }
        }
#pragma unroll
        for (int g_ = 0; g_ < 4; g_++)
#pragma unroll
            for (int b = 0; b < 4; b++) {
                float x = acc[g_][b];
                x += __shfl_xor(x, 8, 64);
                x += __shfl_xor(x, 16, 64);
                x += __shfl_xor(x, 32, 64);
                acc[g_][b] = x;
            }
        {
            int wv = tid >> 6;
            if ((tid & 63) < 8) {
#pragma unroll
                for (int g_ = 0; g_ < 4; g_++)
#pragma unroll
                    for (int b = 0; b < 4; b++)
                        s_part[((wv * 4 + g_) * 8 + cq) * 4 + b] = acc[g_][b];
            }
        }
        __syncthreads();
        if (tid < 128) {
            int c = tid & 31, b = tid >> 5;
            int g_ = c >> 3, jq = c & 7;
            float tot = gxv;
#pragma unroll
            for (int w = 0; w < 4; w++)
                tot += s_part[((w * 4 + g_) * 8 + jq) * 4 + b];
            s_tot[c * 4 + b] = tot;
        }
        __syncthreads();
        if (tid < 32) {
            int jl = tid & 7, b = tid >> 3;
            float gi  = s_tot[(0 * 8 + jl) * 4 + b];
            float gf  = s_tot[(1 * 8 + jl) * 4 + b];
            float gg  = s_tot[(2 * 8 + jl) * 4 + b];
            float go_ = s_tot[(3 * 8 + jl) * 4 + b];
            float cc = sigmf(gf) * c_s[jl * 4 + b] + sigmf(gi) * tanhf(gg);
            float hh = sigmf(go_) * tanhf(cc);
            c_s[jl * 4 + b] = cc;
            int j = bl * 8 + jl;
            int bgl = bg0 + b;
            gst(h_out + bgl * 512 + j, hh);               // coherent
            hr[((size_t)t * 16 + bgl) * 1536 + j] = hh;   // cached sink
            if (t == 127) {
                out[1048576 + bgl * 512 + j] = hh;
                out[1048576 + 8192 + bgl * 512 + j] = cc;
            }
        }
        // publish h (1-hop producer flag replaces the 2-hop barrier)
        post_flag(hf, (unsigned)(t + 1), bi, tid);
        wait_flags(hf, (unsigned)(t + 1), g, tid);

        // ================= phase X: xi = h @ W_int + b_int (2 passes) =====
        {
            // stage h_out (4 x 512), chunk-36 rows
            {
                const float* ph = h_out + (bg0 + b4) * 512 + sg * 4;
                f32x4 e0, e1;
                ld2h(e0, e1, ph);
#define STX(j, E) { int k = sg * 4 + (j) * 256; \
                    *(f32x4*)&big_u[b4 * 592 + (k >> 5) * 36 + (k & 31)] = E; }
                STX(0, e0) STX(1, e1)
#undef STX
            }
            __syncthreads();
#pragma unroll 1
            for (int p = 0; p < 2; p++) {
                if (p == 1 && bl >= 17) break;
                int q0 = p * 2048 + bl * 32;          // contiguous 32-col stripe
                int q  = q0 + xql;
                int qc = (q < 2573) ? q : 2572;
                float wxr[64];
#pragma unroll
                for (int i = 0; i < 64; i++)
                    wxr[i] = W_int[(size_t)(xkcl * 64 + i) * 2573 + qc];
                float ax[4];
#pragma unroll
                for (int b = 0; b < 4; b++) ax[b] = 0.f;
#pragma unroll
                for (int b = 0; b < 4; b++) {
                    const f32x4* hp0 = (const f32x4*)&big_u[b * 592 + (2 * xkcl) * 36];
                    const f32x4* hp1 = (const f32x4*)&big_u[b * 592 + (2 * xkcl + 1) * 36];
#pragma unroll
                    for (int i4 = 0; i4 < 8; i4++) {
                        f32x4 hv = hp0[i4];
                        ax[b] = fmaf(wxr[i4 * 4 + 0], hv[0], ax[b]);
                        ax[b] = fmaf(wxr[i4 * 4 + 1], hv[1], ax[b]);
                        ax[b] = fmaf(wxr[i4 * 4 + 2], hv[2], ax[b]);
                        ax[b] = fmaf(wxr[i4 * 4 + 3], hv[3], ax[b]);
                    }
#pragma unroll
                    for (int i4 = 0; i4 < 8; i4++) {
                        f32x4 hv = hp1[i4];
                        ax[b] = fmaf(wxr[32 + i4 * 4 + 0], hv[0], ax[b]);
                        ax[b] = fmaf(wxr[32 + i4 * 4 + 1], hv[1], ax[b]);
                        ax[b] = fmaf(wxr[32 + i4 * 4 + 2], hv[2], ax[b]);
                        ax[b] = fmaf(wxr[32 + i4 * 4 + 3], hv[3], ax[b]);
                    }
                }
                // reduce over xkcl: lane bit 5 pairs kcl {2w,2w+1}; 4 waves via LDS
#pragma unroll
                for (int b = 0; b < 4; b++) {
                    float x = ax[b];
                    x += __shfl_xor(x, 32, 64);
                    ax[b] = x;
                }
                {
                    int wv = tid >> 6;
                    if ((tid & 63) < 32) {
#pragma unroll
                        for (int b = 0; b < 4; b++)
                            s_part[(wv * 32 + xql) * 4 + b] = ax[b];
                    }
                }
                __syncthreads();
                if (tid < 128) {
                    int q_l = tid >> 2, b = tid & 3;
                    int qq = q0 + q_l;
                    if (qq < 2573) {
                        float v = b_int[qq];
#pragma unroll
                        for (int w = 0; w < 4; w++)
                            v += s_part[(w * 32 + q_l) * 4 + b];
                        gst(&xib[(bg0 + b) * 3072 + qq], v);    // coherent
                    }
                }
                __syncthreads();
            }
        }
        // announce xi completion
        post_flag(xf, (unsigned)(t + 1), bi, tid);

        // ================= phase M: memory machinery (bl 0..3) =================
        if (bl < 4) {
            const int bg = bg0 + bl;
            wait_flags(xf, (unsigned)(t + 1), g, tid);
            {
                const float* xs = xib + bg * 3072;
                f32x4 d0, d1, d2;
                cld3(d0, d1, d2,
                     xs + (tid + 0) * 4, xs + (tid + 256) * 4, xs + (tid + 512) * 4);
                *(f32x4*)&s_xi[(tid + 0) * 4]   = d0;
                *(f32x4*)&s_xi[(tid + 256) * 4] = d1;
                *(f32x4*)&s_xi[(tid + 512) * 4] = d2;
            }
            __syncthreads();
            const float* xb = s_xi;

            if (tid == 0) {
                s_wb = oneplusf(xb[1538]);
                s_ga = sigmf(xb[2565]);
                s_gw = sigmf(xb[2566]);
            }
            if (tid == 1 || tid == 2) {
                int rr = tid - 1;
                s_rb[rr] = oneplusf(xb[1024 + rr]);
                s_fg[rr] = sigmf(xb[2563 + rr]);
                float z0 = xb[2567 + rr * 3], z1 = xb[2568 + rr * 3], z2 = xb[2569 + rr * 3];
                float mx = fmaxf(z0, fmaxf(z1, z2));
                float e0 = expf(z0 - mx), e1 = expf(z1 - mx), e2 = expf(z2 - mx);
                float s = e0 + e1 + e2;
                s_pi[rr][0] = e0 / s; s_pi[rr][1] = e1 / s; s_pi[rr][2] = e2 / s;
            }
            if (tid >= 32 && tid < 42) { int i = tid - 32; s_wrold[i / 5][i % 5] = st_wr[i]; }
            if (tid >= 64 && tid < 69) { s_pold[tid - 64] = st_p[tid - 64]; }
            __syncthreads();
            if (tid < 5) {
                float psi = (1.f - s_fg[0] * s_wrold[0][tid]) * (1.f - s_fg[1] * s_wrold[1][tid]);
                float un = (st_u[tid] + st_ww[tid] - st_u[tid] * st_ww[tid]) * psi;
                s_uu[tid] = un; st_u[tid] = un;
            }
            __syncthreads();
            if (tid < 5) {
                float excl = 1.f;
#pragma unroll
                for (int m2 = 0; m2 < 5; m2++) {
                    bool before = (s_uu[m2] < s_uu[tid]) || (s_uu[m2] == s_uu[tid] && m2 < tid);
                    if (before) excl *= s_uu[m2];
                }
                s_a[tid] = (1.f - s_uu[tid]) * excl;
            }
            float accA[11];
#pragma unroll
            for (int i = 0; i < 11; i++) accA[i] = 0.f;
            for (int w = tid; w < 512; w += 256) {
                float wk = xb[1026 + w];
                accA[10] += wk * wk;
#pragma unroll
                for (int n = 0; n < 5; n++) {
                    float m_ = s_M[n][w];
                    accA[n]     += m_ * m_;
                    accA[5 + n] += wk * m_;
                }
            }
            blk_reduce<11>(accA, s_red, s_dotA, tid);
            if (tid < 5) {
                float sim = s_dotA[5 + tid] /
                            ((sqrtf(s_dotA[10]) + EPSC) * (sqrtf(s_dotA[tid]) + EPSC));
                s_zw[tid] = s_wb * sim;
            }
            __syncthreads();
            if (tid < 5) {
                float mx = s_zw[0];
#pragma unroll
                for (int m2 = 1; m2 < 5; m2++) mx = fmaxf(mx, s_zw[m2]);
                float sum = 0.f;
#pragma unroll
                for (int m2 = 0; m2 < 5; m2++) sum += expf(s_zw[m2] - mx);
                float cw = expf(s_zw[tid] - mx) / sum;
                float w_ = s_gw * (s_ga * s_a[tid] + (1.f - s_ga) * cw);
                s_wwn[tid] = w_; st_ww[tid] = w_;
            }
            __syncthreads();
            float accB[17];
#pragma unroll
            for (int i = 0; i < 17; i++) accB[i] = 0.f;
            for (int w = tid; w < 512; w += 256) {
                float ew = sigmf(xb[1539 + w]);
                float vw = xb[2051 + w];
                float rk0 = xb[w], rk1 = xb[512 + w];
                accB[15] += rk0 * rk0; accB[16] += rk1 * rk1;
#pragma unroll
                for (int n = 0; n < 5; n++) {
                    float m_ = s_M[n][w];
                    float mn_ = m_ * (1.f - s_wwn[n] * ew) + s_wwn[n] * vw;
                    s_M[n][w] = mn_;
                    accB[n]      += mn_ * mn_;
                    accB[5 + n]  += rk0 * mn_;
                    accB[10 + n] += rk1 * mn_;
                }
            }
            blk_reduce<17>(accB, s_red, s_dotB, tid);
            if (tid < 25) {
                int i2 = tid / 5, j2 = tid % 5;
                float Ln = (i2 == j2) ? 0.f
                         : (1.f - s_wwn[i2] - s_wwn[j2]) * st_L[tid] + s_wwn[i2] * s_pold[j2];
                s_Lnew[tid] = Ln; st_L[tid] = Ln;
            }
            __syncthreads();
            if (tid < 5) {
                float wsum = s_wwn[0] + s_wwn[1] + s_wwn[2] + s_wwn[3] + s_wwn[4];
                st_p[tid] = (1.f - wsum) * s_pold[tid] + s_wwn[tid];
            }
            if (tid < 10) {
                int rr = tid / 5, ii = tid % 5;
                float fw = 0.f, bw = 0.f;
#pragma unroll
                for (int j2 = 0; j2 < 5; j2++) {
                    fw += s_Lnew[ii * 5 + j2] * s_wrold[rr][j2];
                    bw += s_Lnew[j2 * 5 + ii] * s_wrold[rr][j2];
                }
                s_fw[rr][ii] = fw; s_bw[rr][ii] = bw;
                float sim = s_dotB[5 + rr * 5 + ii] /
                            ((sqrtf(s_dotB[15 + rr]) + EPSC) * (sqrtf(s_dotB[ii]) + EPSC));
                s_z[rr][ii] = s_rb[rr] * sim;
            }
            __syncthreads();
            if (tid < 10) {
                int rr = tid / 5, ii = tid % 5;
                float mx = s_z[rr][0];
#pragma unroll
                for (int m2 = 1; m2 < 5; m2++) mx = fmaxf(mx, s_z[rr][m2]);
                float sum = 0.f;
#pragma unroll
                for (int m2 = 0; m2 < 5; m2++) sum += expf(s_z[rr][m2] - mx);
                float cr = expf(s_z[rr][ii] - mx) / sum;
                float wn = s_pi[rr][0] * s_bw[rr][ii] + s_pi[rr][1] * cr + s_pi[rr][2] * s_fw[rr][ii];
                s_wrnew[rr][ii] = wn; st_wr[rr * 5 + ii] = wn;
            }
            __syncthreads();
            for (int idx = tid; idx < 1024; idx += 256) {
                int rr = idx >> 9, w = idx & 511;
                float rv = 0.f;
#pragma unroll
                for (int n = 0; n < 5; n++) rv += s_wrnew[rr][n] * s_M[n][w];
                gst(&rbuf[bg * 1024 + idx], rv);        // coherent
                hr[((size_t)t * 16 + bg) * 1536 + 512 + idx] = rv;
            }
            post_flag(rf, (unsigned)(t + 1), bg, tid);
        }
        // non-M blocks: straight to next rf-wait
    }
}

// ---------------------------------------------------------------------------
// Prologue: gates_x[tok][col] = b_lstm[col] + sum_{k<512} emb[src_tok,k]*W_ih[col,k]
// ---------------------------------------------------------------------------
__global__ __launch_bounds__(256) void k_embgx(
    const int* __restrict__ src, const float* __restrict__ emb,
    const float* __restrict__ W_ih, const float* __restrict__ b_lstm,
    float* __restrict__ gx)
{
    __shared__ __align__(16) float As[16][68];
    __shared__ __align__(16) float Bs[16][68];
    const int tid = threadIdx.x;
    const int bm = blockIdx.x, bn = blockIdx.y;
    const int tm = tid >> 4, tn = tid & 15;
    float acc[4][4] = {};
    for (int k0 = 0; k0 < 512; k0 += 16) {
#pragma unroll
        for (int i = 0; i < 4; i++) {
            int idx = tid + 256 * i;
            int m = idx >> 4, kk = idx & 15;
            int tok = bm * 64 + m;
            int row = src[(tok & 15) * 128 + (tok >> 4)];
            As[kk][m] = emb[(size_t)row * 512 + k0 + kk];
        }
#pragma unroll
        for (int i = 0; i < 4; i++) {
            int idx = tid + 256 * i;
            int n = idx >> 4, kk = idx & 15;
            Bs[kk][n] = W_ih[(size_t)(bn * 64 + n) * 1536 + k0 + kk];
        }
        __syncthreads();
#pragma unroll
        for (int kk = 0; kk < 16; kk++) {
            float4 av = *(const float4*)&As[kk][tm * 4];
            float4 bv = *(const float4*)&Bs[kk][tn * 4];
            float a[4] = {av.x, av.y, av.z, av.w};
            float b[4] = {bv.x, bv.y, bv.z, bv.w};
#pragma unroll
            for (int i = 0; i < 4; i++)
#pragma unroll
                for (int j = 0; j < 4; j++) acc[i][j] = fmaf(a[i], b[j], acc[i][j]);
        }
        __syncthreads();
    }
#pragma unroll
    for (int i = 0; i < 4; i++) {
        int tok = bm * 64 + tm * 4 + i;
#pragma unroll
        for (int j = 0; j < 4; j++) {
            int col = bn * 64 + tn * 4 + j;
            gx[(size_t)tok * 2048 + col] = acc[i][j] + b_lstm[col];
        }
    }
}

// ---------------------------------------------------------------------------
// Epilogue: out[b,s,q] = b_out[q] + sum_k hr[s,b,k]*W_out[k,q]
// ---------------------------------------------------------------------------
__global__ __launch_bounds__(256) void k_out(
    const float* __restrict__ hr, const float* __restrict__ W_out,
    const float* __restrict__ b_out, float* __restrict__ out)
{
    __shared__ __align__(16) float As[16][68];
    __shared__ __align__(16) float Bs[16][68];
    const int tid = threadIdx.x;
    const int bm = blockIdx.x, bn = blockIdx.y;
    const int tm = tid >> 4, tn = tid & 15;
    float acc[4][4] = {};
    for (int k0 = 0; k0 < 1536; k0 += 16) {
#pragma unroll
        for (int i = 0; i < 4; i++) {
            int idx = tid + 256 * i;
            int m = idx >> 4, kk = idx & 15;
            As[kk][m] = hr[(size_t)(bm * 64 + m) * 1536 + k0 + kk];
        }
#pragma unroll
        for (int i = 0; i < 4; i++) {
            int idx = tid + 256 * i;
            int kk = idx >> 6, n = idx & 63;
            Bs[kk][n] = W_out[(size_t)(k0 + kk) * 512 + bn * 64 + n];
        }
        __syncthreads();
#pragma unroll
        for (int kk = 0; kk < 16; kk++) {
            float4 av = *(const float4*)&As[kk][tm * 4];
            float4 bv = *(const float4*)&Bs[kk][tn * 4];
            float a[4] = {av.x, av.y, av.z, av.w};
            float b[4] = {bv.x, bv.y, bv.z, bv.w};
#pragma unroll
            for (int i = 0; i < 4; i++)
#pragma unroll
                for (int j = 0; j < 4; j++) acc[i][j] = fmaf(a[i], b[j], acc[i][j]);
        }
        __syncthreads();
    }
#pragma unroll
    for (int i = 0; i < 4; i++) {
        int tok = bm * 64 + tm * 4 + i;
        int b_ = tok & 15, s_ = tok >> 4;
#pragma unroll
        for (int j = 0; j < 4; j++) {
            int qn = bn * 64 + tn * 4 + j;
            out[(size_t)((b_ << 7) + s_) * 512 + qn] = acc[i][j] + b_out[qn];
        }
    }
}

extern "C" void kernel_launch(void* const* d_in, const int* in_sizes, int n_in,
                              void* d_out, int out_size, void* d_ws, size_t ws_size,
                              hipStream_t stream)
{
    const int*   src    = (const int*)d_in[0];
    const float* emb    = (const float*)d_in[2];
    const float* W_ih   = (const float*)d_in[3];
    const float* W_hh   = (const float*)d_in[4];
    const float* b_lstm = (const float*)d_in[5];
    const float* W_int  = (const float*)d_in[6];
    const float* b_int  = (const float*)d_in[7];
    const float* W_out  = (const float*)d_in[8];
    const float* b_out  = (const float*)d_in[9];

    float* ws  = (float*)d_ws;
    float* out = (float*)d_out;

    float*    hbuf = ws + OFF_H;
    float*    rbuf = ws + OFF_R;
    unsigned* hf   = (unsigned*)(ws + OFF_HF);
    unsigned* xf   = (unsigned*)(ws + OFF_XF);
    unsigned* rf   = (unsigned*)(ws + OFF_RF);
    float*    xib  = ws + OFF_XI;
    float*    gx   = ws + OFF_GX;
    float*    hrb  = ws + OFF_HR;

    // zero recurrent state + all sync flags (deterministic across replays)
    hipMemsetAsync(ws, 0, STATE_END * sizeof(float), stream);

    // prologue: token-parallel x-part of gates (+ bias)
    k_embgx<<<dim3(32, 32), 256, 0, stream>>>(src, emb, W_ih, b_lstm, gx);

    // main loop: 4 independent 64-block groups (4 batches each), 256 blocks
    k_main<<<dim3(NBLK), dim3(256), 0, stream>>>(
        W_ih, W_hh, W_int, b_int, gx, hbuf, rbuf, xib, hrb, out,
        hf, xf, rf);

    // epilogue: token-parallel output projection
    k_out<<<dim3(32, 8), 256, 0, stream>>>(hrb, W_out, b_out, out);
}